// Round 1
// baseline (2176.440 us; speedup 1.0000x reference)
//
#include <hip/hip_runtime.h>
#include <math.h>

// Problem constants (from reference): x (64,512,256) f32, codebook (8192,256) f32
#define N_TOK 32768   // 64*512 tokens
#define DDIM  256
#define KCB   8192
#define KSLICES 4
#define KS    (KCB / KSLICES)   // 2048 codes per slice
#define TM 64
#define TN 64
#define BK 32
#define PAD 4   // +4 float pad keeps 16B alignment for ds_read_b128, breaks worst bank conflicts

// K0: codebook row squared-norms; block 0 also zeroes the loss accumulator slot.
__global__ __launch_bounds__(64) void cnorm_kernel(const float* __restrict__ cb,
                                                   float* __restrict__ cnorm,
                                                   float* __restrict__ out) {
    int code = blockIdx.x;
    int lane = threadIdx.x;
    const float4* row = (const float4*)(cb + (size_t)code * DDIM);
    float4 v = row[lane];                       // 64 lanes * 4 floats = 256
    float s = v.x * v.x + v.y * v.y + v.z * v.z + v.w * v.w;
    #pragma unroll
    for (int off = 32; off > 0; off >>= 1) s += __shfl_down(s, off);
    if (lane == 0) cnorm[code] = s;
    if (code == 0 && lane == 0) out[(size_t)N_TOK * DDIM] = 0.0f;  // loss slot
}

// K1: per (64-token tile, K-slice): fused distance GEMM + running argmin.
// dist(n,k) = ||c_k||^2 - 2 * x_n . c_k   (same argmin as reference's full L2)
__global__ __launch_bounds__(256) void argmin_partial(
    const float* __restrict__ x, const float* __restrict__ cb,
    const float* __restrict__ cnorm,
    float* __restrict__ bestd_out, int* __restrict__ besti_out) {

    const int tileM    = blockIdx.x;       // 512 token tiles
    const int slice    = blockIdx.y;       // 4 K-slices
    const int tokBase  = tileM * TM;
    const int codeBase0 = slice * KS;

    __shared__ float As[BK][TM + PAD];
    __shared__ float Bs[BK][TN + PAD];

    const int tid = threadIdx.x;
    const int tx = tid & 15;               // code group (4 consecutive codes)
    const int ty = tid >> 4;               // token group (4 consecutive tokens)

    float bestd[4];
    int   besti[4];
    #pragma unroll
    for (int i = 0; i < 4; i++) { bestd[i] = INFINITY; besti[i] = 0; }

    for (int ct = 0; ct < KS / TN; ct++) {           // 32 code tiles per slice
        const int codeBase = codeBase0 + ct * TN;
        float acc[4][4] = {};

        for (int dk = 0; dk < DDIM; dk += BK) {      // 8 D-chunks
            __syncthreads();
            #pragma unroll
            for (int s = 0; s < 8; s++) {            // 2048 elems, 8/thread, coalesced 32-float rows
                int e = tid + 256 * s;
                int r = e >> 5;                      // row within tile (token / code)
                int d = e & 31;                      // dim within chunk
                As[d][r] = x [(size_t)(tokBase  + r) * DDIM + dk + d];
                Bs[d][r] = cb[(size_t)(codeBase + r) * DDIM + dk + d];
            }
            __syncthreads();
            #pragma unroll
            for (int kk = 0; kk < BK; kk++) {
                float4 a = *(const float4*)&As[kk][ty * 4];   // 4 contiguous tokens
                float4 b = *(const float4*)&Bs[kk][tx * 4];   // 4 contiguous codes
                float av[4] = {a.x, a.y, a.z, a.w};
                float bv[4] = {b.x, b.y, b.z, b.w};
                #pragma unroll
                for (int i = 0; i < 4; i++)
                    #pragma unroll
                    for (int j = 0; j < 4; j++)
                        acc[i][j] += av[i] * bv[j];
            }
        }
        // distances + running argmin (strict < keeps lowest index on exact ties,
        // since code index ascends across j and ct)
        #pragma unroll
        for (int j = 0; j < 4; j++) {
            int code = codeBase + tx * 4 + j;
            float cn = cnorm[code];
            #pragma unroll
            for (int i = 0; i < 4; i++) {
                float d = cn - 2.0f * acc[i][j];
                if (d < bestd[i]) { bestd[i] = d; besti[i] = code; }
            }
        }
    }

    // reduce across the 16 tx threads per token
    __shared__ float red_d[TM][17];
    __shared__ int   red_i[TM][17];
    __syncthreads();
    #pragma unroll
    for (int i = 0; i < 4; i++) {
        red_d[ty * 4 + i][tx] = bestd[i];
        red_i[ty * 4 + i][tx] = besti[i];
    }
    __syncthreads();
    if (tid < TM) {
        float bd = red_d[tid][0];
        int   bi = red_i[tid][0];
        #pragma unroll
        for (int t = 1; t < 16; t++) {
            float d = red_d[tid][t];
            int   id = red_i[tid][t];
            if (d < bd || (d == bd && id < bi)) { bd = d; bi = id; }
        }
        int tok = tokBase + tid;
        bestd_out[(size_t)tok * KSLICES + slice] = bd;
        besti_out[(size_t)tok * KSLICES + slice] = bi;
    }
}

// K2: merge K-slices, gather quantized rows, accumulate commitment loss.
__global__ __launch_bounds__(256) void finalize_kernel(
    const float* __restrict__ x, const float* __restrict__ cb,
    const float* __restrict__ bestd_in, const int* __restrict__ besti_in,
    float* __restrict__ out) {

    const int tokBase = blockIdx.x * TM;   // 512 blocks
    const int tid = threadIdx.x;

    __shared__ int fidx[TM];
    if (tid < TM) {
        int tok = tokBase + tid;
        float bd = INFINITY;
        int   bi = 0;
        #pragma unroll
        for (int s = 0; s < KSLICES; s++) {
            float d = bestd_in[(size_t)tok * KSLICES + s];
            int   id = besti_in[(size_t)tok * KSLICES + s];
            if (d < bd || (d == bd && id < bi)) { bd = d; bi = id; }
        }
        fidx[tid] = bi;
    }
    __syncthreads();

    float lsum = 0.0f;
    for (int e = tid; e < TM * DDIM; e += 256) {     // 64 iters/thread, coalesced
        int tok = e >> 8;
        int d   = e & 255;
        float q  = cb[(size_t)fidx[tok] * DDIM + d];
        float xv = x [(size_t)(tokBase + tok) * DDIM + d];
        float df = q - xv;
        lsum += df * df;
        out[(size_t)(tokBase + tok) * DDIM + d] = q;
    }

    __shared__ float red[256];
    red[tid] = lsum;
    __syncthreads();
    #pragma unroll
    for (int s = 128; s > 0; s >>= 1) {
        if (tid < s) red[tid] += red[tid + s];
        __syncthreads();
    }
    if (tid == 0)
        atomicAdd(out + (size_t)N_TOK * DDIM,
                  red[0] * (0.25f / (float)((size_t)N_TOK * DDIM)));
}

extern "C" void kernel_launch(void* const* d_in, const int* in_sizes, int n_in,
                              void* d_out, int out_size, void* d_ws, size_t ws_size,
                              hipStream_t stream) {
    const float* x  = (const float*)d_in[0];   // 8388608 f32
    const float* cb = (const float*)d_in[1];   // 2097152 f32
    float* out = (float*)d_out;                // 8388608 quantized + 1 loss

    // ws layout: cnorm[8192] | bestd[N*4] | besti[N*4]  (~1.03 MB)
    float* cnorm = (float*)d_ws;
    float* bestd = cnorm + KCB;
    int*   besti = (int*)(bestd + (size_t)N_TOK * KSLICES);

    cnorm_kernel<<<KCB, 64, 0, stream>>>(cb, cnorm, out);
    dim3 g1(N_TOK / TM, KSLICES);
    argmin_partial<<<g1, 256, 0, stream>>>(x, cb, cnorm, bestd, besti);
    finalize_kernel<<<N_TOK / TM, 256, 0, stream>>>(x, cb, bestd, besti, out);
}

// Round 2
// 829.948 us; speedup vs baseline: 2.6224x; 2.6224x over previous
//
#include <hip/hip_runtime.h>
#include <math.h>

// x: (64,512,256) f32 -> 32768 tokens x 256 dims. codebook: (8192,256) f32.
#define N_TOK 32768
#define DDIM  256
#define KCB   8192
#define SLICES 4
#define KS    (KCB / SLICES)   // 2048 codes per slice
#define NSTEP (KS / 64)        // 32 code-tiles of 64 per slice

typedef _Float16 half_t;
typedef half_t half8 __attribute__((ext_vector_type(8)));
typedef float  f32x4 __attribute__((ext_vector_type(4)));

// ---------------------------------------------------------------------------
// K0: fp32 codebook row norms; block 0 zeroes the loss slot.
__global__ __launch_bounds__(64) void cnorm_kernel(const float* __restrict__ cb,
                                                   float* __restrict__ cnorm,
                                                   float* __restrict__ out) {
    int code = blockIdx.x;
    int lane = threadIdx.x;
    const f32x4* row = (const f32x4*)(cb + (size_t)code * DDIM);
    f32x4 v = row[lane];
    float s = v[0]*v[0] + v[1]*v[1] + v[2]*v[2] + v[3]*v[3];
    #pragma unroll
    for (int off = 32; off > 0; off >>= 1) s += __shfl_down(s, off);
    if (lane == 0) cnorm[code] = s;
    if (code == 0 && lane == 0) out[(size_t)N_TOK * DDIM] = 0.0f;
}

// ---------------------------------------------------------------------------
// load 8 consecutive f32, convert to 8 f16
__device__ __forceinline__ half8 ldcvt8(const float* __restrict__ p) {
    f32x4 a = *(const f32x4*)p;
    f32x4 b = *(const f32x4*)(p + 4);
    half8 h;
    h[0] = (half_t)a[0]; h[1] = (half_t)a[1]; h[2] = (half_t)a[2]; h[3] = (half_t)a[3];
    h[4] = (half_t)b[0]; h[5] = (half_t)b[1]; h[6] = (half_t)b[2]; h[7] = (half_t)b[3];
    return h;
}

// ---------------------------------------------------------------------------
// Pass A: f16 MFMA distance scan. Block = 512 threads (8 waves), 512 tokens,
// one K-slice of 2048 codes. Wave tile = 64 tokens x 64 codes, 16x16x32 MFMA.
// A (x) fragments persistent in registers; codebook double-buffered in LDS
// with XOR-swizzled 16B chunks. Output: top-2 candidate code ids per
// (token, slice), by approximate distance cnorm - 2*dot_f16.
__global__ __launch_bounds__(512, 2) void passA(
    const float* __restrict__ x, const float* __restrict__ cb,
    const float* __restrict__ cnorm, int* __restrict__ cand_i) {

    __shared__ half_t buf[2][64][256];   // 64 KB: 2 x (64 rows x 256 halves)

    const int tid  = threadIdx.x;
    const int w    = tid >> 6;           // wave 0..7
    const int lane = tid & 63;
    const int quad = lane >> 4;          // 0..3
    const int mcol = lane & 15;          // MFMA row (A) / col (B,C) index
    const int tokBase   = blockIdx.x * 512;
    const int codeBase0 = blockIdx.y * KS;

    // ---- preload A fragments: token rows (w*64 + rt*16 + mcol), all D.
    // A[m][k]: m = lane&15, k = quad*8 + j  (16x16x32 f16 layout)
    half8 afrag[4][8];
    for (int ch = 0; ch < 8; ch++) {
        __syncthreads();                              // buffer reuse guard
        const float* src = x + (size_t)(tokBase + ch * 64) * DDIM;
        #pragma unroll
        for (int o = 0; o < 4; o++) {
            int e = tid + 512 * o;                    // 0..2047
            int r = e >> 5;                           // row in tile
            int c = e & 31;                           // 16B chunk in row
            int cs = c ^ (r & 7);                     // XOR swizzle
            *(half8*)&buf[0][r][cs * 8] = ldcvt8(src + r * DDIM + c * 8);
        }
        __syncthreads();
        if (w == ch) {
            #pragma unroll
            for (int rt = 0; rt < 4; rt++)
                #pragma unroll
                for (int dk = 0; dk < 8; dk++) {
                    int cc = (dk * 4 + quad) ^ (mcol & 7);
                    afrag[rt][dk] = *(const half8*)&buf[0][rt * 16 + mcol][cc * 8];
                }
        }
    }

    // ---- per-lane top-2 trackers, one per owned token [rt][reg]
    float bd0[4][4], bd1[4][4];
    int   bi0[4][4], bi1[4][4];
    #pragma unroll
    for (int rt = 0; rt < 4; rt++)
        #pragma unroll
        for (int r = 0; r < 4; r++) {
            bd0[rt][r] = INFINITY; bd1[rt][r] = INFINITY;
            bi0[rt][r] = 0;        bi1[rt][r] = 0;
        }

    // ---- codebook tile pipeline: regs(next) -> LDS(double buffer)
    half8 pf[4];
    {
        const float* src = cb + (size_t)codeBase0 * DDIM;
        #pragma unroll
        for (int o = 0; o < 4; o++) {
            int e = tid + 512 * o, r = e >> 5, c = e & 31;
            pf[o] = ldcvt8(src + r * DDIM + c * 8);
        }
    }
    __syncthreads();                                  // protect last A-read
    #pragma unroll
    for (int o = 0; o < 4; o++) {
        int e = tid + 512 * o, r = e >> 5, c = e & 31, cs = c ^ (r & 7);
        *(half8*)&buf[0][r][cs * 8] = pf[o];
    }
    {
        const float* src = cb + (size_t)(codeBase0 + 64) * DDIM;
        #pragma unroll
        for (int o = 0; o < 4; o++) {
            int e = tid + 512 * o, r = e >> 5, c = e & 31;
            pf[o] = ldcvt8(src + r * DDIM + c * 8);
        }
    }
    __syncthreads();

    for (int nt = 0; nt < NSTEP; nt++) {
        const half_t (*cur)[256] = buf[nt & 1];
        const int codeBase = codeBase0 + nt * 64;

        // prefetch cnorm for the 4 column tiles (latency hidden over MFMAs)
        float cnv[4];
        #pragma unroll
        for (int ct = 0; ct < 4; ct++) cnv[ct] = cnorm[codeBase + ct * 16 + mcol];

        #pragma unroll
        for (int ct = 0; ct < 4; ct++) {
            f32x4 acc[4] = {};
            #pragma unroll
            for (int dk = 0; dk < 8; dk++) {
                int cc = (dk * 4 + quad) ^ (mcol & 7);
                half8 bf = *(const half8*)&cur[ct * 16 + mcol][cc * 8];
                acc[0] = __builtin_amdgcn_mfma_f32_16x16x32_f16(afrag[0][dk], bf, acc[0], 0, 0, 0);
                acc[1] = __builtin_amdgcn_mfma_f32_16x16x32_f16(afrag[1][dk], bf, acc[1], 0, 0, 0);
                acc[2] = __builtin_amdgcn_mfma_f32_16x16x32_f16(afrag[2][dk], bf, acc[2], 0, 0, 0);
                acc[3] = __builtin_amdgcn_mfma_f32_16x16x32_f16(afrag[3][dk], bf, acc[3], 0, 0, 0);
            }
            // C layout: col = lane&15 (code), row = quad*4 + reg (token)
            const int code = codeBase + ct * 16 + mcol;
            const float cn = cnv[ct];
            #pragma unroll
            for (int rt = 0; rt < 4; rt++)
                #pragma unroll
                for (int r = 0; r < 4; r++) {
                    float v = fmaf(-2.0f, acc[rt][r], cn);
                    if (v < bd0[rt][r]) {
                        bd1[rt][r] = bd0[rt][r]; bi1[rt][r] = bi0[rt][r];
                        bd0[rt][r] = v;          bi0[rt][r] = code;
                    } else if (v < bd1[rt][r]) {
                        bd1[rt][r] = v;          bi1[rt][r] = code;
                    }
                }
        }

        if (nt + 1 < NSTEP) {
            #pragma unroll
            for (int o = 0; o < 4; o++) {
                int e = tid + 512 * o, r = e >> 5, c = e & 31, cs = c ^ (r & 7);
                *(half8*)&buf[(nt + 1) & 1][r][cs * 8] = pf[o];
            }
            if (nt + 2 < NSTEP) {
                const float* src = cb + (size_t)(codeBase0 + (nt + 2) * 64) * DDIM;
                #pragma unroll
                for (int o = 0; o < 4; o++) {
                    int e = tid + 512 * o, r = e >> 5, c = e & 31;
                    pf[o] = ldcvt8(src + r * DDIM + c * 8);
                }
            }
        }
        __syncthreads();
    }

    // ---- butterfly-merge top-2 across the 16 class lanes (same quad group
    // holds the same 16 tokens), then lane mcol==0 writes top-2 per token.
    #pragma unroll
    for (int s = 1; s < 16; s <<= 1) {
        #pragma unroll
        for (int rt = 0; rt < 4; rt++)
            #pragma unroll
            for (int r = 0; r < 4; r++) {
                float od0 = __shfl_xor(bd0[rt][r], s, 64);
                int   oi0 = __shfl_xor(bi0[rt][r], s, 64);
                float od1 = __shfl_xor(bd1[rt][r], s, 64);
                int   oi1 = __shfl_xor(bi1[rt][r], s, 64);
                float a0 = bd0[rt][r], a1 = bd1[rt][r];
                int   y0 = bi0[rt][r], y1 = bi1[rt][r];
                bool ofirst = (od0 < a0) || (od0 == a0 && oi0 < y0);
                if (ofirst) {
                    bool t = (a0 < od1) || (a0 == od1 && y0 < oi1);
                    bd0[rt][r] = od0;            bi0[rt][r] = oi0;
                    bd1[rt][r] = t ? a0 : od1;   bi1[rt][r] = t ? y0 : oi1;
                } else {
                    bool t = (od0 < a1) || (od0 == a1 && oi0 < y1);
                    bd1[rt][r] = t ? od0 : a1;   bi1[rt][r] = t ? oi0 : y1;
                }
            }
    }
    if (mcol == 0) {
        #pragma unroll
        for (int rt = 0; rt < 4; rt++)
            #pragma unroll
            for (int r = 0; r < 4; r++) {
                int token = tokBase + w * 64 + rt * 16 + quad * 4 + r;
                size_t base = (size_t)token * (SLICES * 2) + blockIdx.y * 2;
                cand_i[base]     = bi0[rt][r];
                cand_i[base + 1] = bi1[rt][r];
            }
    }
}

// ---------------------------------------------------------------------------
// K2: exact fp32 re-score of the 8 candidates per token; gather winner row,
// accumulate commitment loss. One wave per 16 tokens, 64 tokens per block.
__global__ __launch_bounds__(256) void finalize_kernel(
    const float* __restrict__ x, const float* __restrict__ cb,
    const float* __restrict__ cnorm, const int* __restrict__ cand_i,
    float* __restrict__ out) {

    const int tid = threadIdx.x, w = tid >> 6, lane = tid & 63;
    float lsum = 0.0f;

    #pragma unroll 1
    for (int i = 0; i < 16; i++) {
        const int token = blockIdx.x * 64 + w * 16 + i;
        f32x4 xv = *(const f32x4*)(x + (size_t)token * DDIM + lane * 4);
        float best = INFINITY;
        int   bidx = 0x7fffffff;
        #pragma unroll
        for (int j = 0; j < 8; j++) {
            int cidx = cand_i[(size_t)token * 8 + j];
            f32x4 cv = *(const f32x4*)(cb + (size_t)cidx * DDIM + lane * 4);
            float p = xv[0]*cv[0] + xv[1]*cv[1] + xv[2]*cv[2] + xv[3]*cv[3];
            #pragma unroll
            for (int off = 32; off > 0; off >>= 1) p += __shfl_xor(p, off, 64);
            float d = cnorm[cidx] - 2.0f * p;
            if (d < best || (d == best && cidx < bidx)) { best = d; bidx = cidx; }
        }
        f32x4 cv = *(const f32x4*)(cb + (size_t)bidx * DDIM + lane * 4);
        *(f32x4*)(out + (size_t)token * DDIM + lane * 4) = cv;
        float d0 = cv[0]-xv[0], d1 = cv[1]-xv[1], d2 = cv[2]-xv[2], d3 = cv[3]-xv[3];
        lsum += d0*d0 + d1*d1 + d2*d2 + d3*d3;
    }

    __shared__ float red[256];
    red[tid] = lsum;
    __syncthreads();
    #pragma unroll
    for (int s = 128; s > 0; s >>= 1) {
        if (tid < s) red[tid] += red[tid + s];
        __syncthreads();
    }
    if (tid == 0)
        atomicAdd(out + (size_t)N_TOK * DDIM,
                  red[0] * (0.25f / (float)((size_t)N_TOK * DDIM)));
}

// ---------------------------------------------------------------------------
extern "C" void kernel_launch(void* const* d_in, const int* in_sizes, int n_in,
                              void* d_out, int out_size, void* d_ws, size_t ws_size,
                              hipStream_t stream) {
    const float* x  = (const float*)d_in[0];
    const float* cb = (const float*)d_in[1];
    float* out = (float*)d_out;

    // ws: cnorm[8192] f32 | cand_i[32768*8] int  (~1.06 MB)
    float* cnorm  = (float*)d_ws;
    int*   cand_i = (int*)(cnorm + KCB);

    cnorm_kernel<<<KCB, 64, 0, stream>>>(cb, cnorm, out);
    dim3 gA(N_TOK / 512, SLICES);
    passA<<<gA, 512, 0, stream>>>(x, cb, cnorm, cand_i);
    finalize_kernel<<<N_TOK / 64, 256, 0, stream>>>(x, cb, cnorm, cand_i, out);
}

// Round 3
// 454.873 us; speedup vs baseline: 4.7847x; 1.8246x over previous
//
#include <hip/hip_runtime.h>
#include <math.h>

// x: (64,512,256) f32 -> 32768 tokens x 256 dims. codebook: (8192,256) f32.
#define N_TOK 32768
#define DDIM  256
#define KCB   8192
#define SLICES 4
#define KS    (KCB / SLICES)   // 2048 codes per slice
#define NSTEP (KS / 64)        // 32 code-tiles of 64 per slice

typedef _Float16 half_t;
typedef half_t half8 __attribute__((ext_vector_type(8)));
typedef half_t half4 __attribute__((ext_vector_type(4)));
typedef float  f32x4 __attribute__((ext_vector_type(4)));

#define GLOBAL_AS __attribute__((address_space(1)))
#define LDS_AS    __attribute__((address_space(3)))

// ---------------------------------------------------------------------------
// P0: codebook f32 -> f16 copy + fp32 row norms; block 0 zeroes loss slot.
__global__ __launch_bounds__(64) void prep_cb(const float* __restrict__ cb,
                                              half_t* __restrict__ cb16,
                                              float* __restrict__ cnorm,
                                              float* __restrict__ out) {
    int code = blockIdx.x;
    int lane = threadIdx.x;
    f32x4 v = *(const f32x4*)(cb + (size_t)code * DDIM + lane * 4);
    half4 h; h[0]=(half_t)v[0]; h[1]=(half_t)v[1]; h[2]=(half_t)v[2]; h[3]=(half_t)v[3];
    *(half4*)(cb16 + (size_t)code * DDIM + lane * 4) = h;
    float s = v[0]*v[0] + v[1]*v[1] + v[2]*v[2] + v[3]*v[3];
    #pragma unroll
    for (int off = 32; off > 0; off >>= 1) s += __shfl_down(s, off);
    if (lane == 0) cnorm[code] = s;
    if (code == 0 && lane == 0) out[(size_t)N_TOK * DDIM] = 0.0f;
}

// load 8 consecutive f32, convert to 8 f16 (prologue only)
__device__ __forceinline__ half8 ldcvt8(const float* __restrict__ p) {
    f32x4 a = *(const f32x4*)p;
    f32x4 b = *(const f32x4*)(p + 4);
    half8 h;
    h[0]=(half_t)a[0]; h[1]=(half_t)a[1]; h[2]=(half_t)a[2]; h[3]=(half_t)a[3];
    h[4]=(half_t)b[0]; h[5]=(half_t)b[1]; h[6]=(half_t)b[2]; h[7]=(half_t)b[3];
    return h;
}

// ---------------------------------------------------------------------------
// Pass A: 256 threads (4 waves), 256 tokens/block, one 2048-code K-slice.
// Wave tile 64 tokens x 64 codes, 16x16x32 f16 MFMA. A fragments in regs
// (loaded once from global f32, converted). B staged from pre-converted f16
// codebook via global_load_lds (async, double-buffered, swizzled layout).
__global__ __launch_bounds__(256)
__attribute__((amdgpu_waves_per_eu(2, 2)))
void passA(const float* __restrict__ x, const half_t* __restrict__ cb16,
           const float* __restrict__ cnorm, int* __restrict__ cand_i) {

    __shared__ __align__(16) half_t buf[2][64 * 256];   // 2 x 32 KB

    const int tid  = threadIdx.x;
    const int w    = tid >> 6;
    const int lane = tid & 63;
    const int quad = lane >> 4;
    const int mcol = lane & 15;
    const int tokBase   = blockIdx.x * 256 + w * 64;   // wave's 64 tokens
    const int codeBase0 = blockIdx.y * KS;

    // ---- A fragments: A[m=mcol][k=quad*8+j], full D in regs (128 VGPRs)
    half8 afrag[4][8];
    #pragma unroll
    for (int rt = 0; rt < 4; rt++) {
        const float* xr = x + (size_t)(tokBase + rt * 16 + mcol) * DDIM + quad * 8;
        #pragma unroll
        for (int dk = 0; dk < 8; dk++)
            afrag[rt][dk] = ldcvt8(xr + dk * 32);
    }

    // ---- staging source offsets: chunk L = o*256+tid, r=L>>5, c=(L&31)^(r&7)
    int goff[8];
    #pragma unroll
    for (int o = 0; o < 8; o++) {
        int L = o * 256 + tid, r = L >> 5, c = (L & 31) ^ (r & 7);
        goff[o] = r * 512 + c * 16;                     // bytes within 64-row tile
    }

    float bd0[4][4], bd1[4][4];
    int   bi0[4][4], bi1[4][4];
    #pragma unroll
    for (int rt = 0; rt < 4; rt++)
        #pragma unroll
        for (int r = 0; r < 4; r++) {
            bd0[rt][r] = INFINITY; bd1[rt][r] = INFINITY;
            bi0[rt][r] = 0;        bi1[rt][r] = 0;
        }

    // stage tile nt into buffer b (async: 8 x 1KB/wave, block moves 32 KB)
    const char* cbbase = (const char*)(cb16 + (size_t)codeBase0 * DDIM);
    #define STAGE(nt, b)                                                        \
        {                                                                       \
            const char* srcb = cbbase + (size_t)(nt) * (64 * 512);              \
            _Pragma("unroll")                                                   \
            for (int o = 0; o < 8; o++) {                                       \
                __builtin_amdgcn_global_load_lds(                               \
                    (const GLOBAL_AS void*)(srcb + goff[o]),                    \
                    (LDS_AS void*)&buf[b][(o * 256 + w * 64) * 8], 16, 0, 0);   \
            }                                                                   \
        }

    STAGE(0, 0)
    __syncthreads();

    for (int nt = 0; nt < NSTEP; nt++) {
        if (nt + 1 < NSTEP) STAGE(nt + 1, (nt + 1) & 1)

        const half_t* cur = buf[nt & 1];
        const int codeBase = codeBase0 + nt * 64;

        float cnv[4];
        #pragma unroll
        for (int ct = 0; ct < 4; ct++) cnv[ct] = cnorm[codeBase + ct * 16 + mcol];

        #pragma unroll
        for (int ct = 0; ct < 4; ct++) {
            const half_t* brow = cur + (ct * 16 + mcol) * 256;
            f32x4 acc[4] = {};
            #pragma unroll
            for (int dk = 0; dk < 8; dk++) {
                int cc = (dk * 4 + quad) ^ (mcol & 7);
                half8 bf = *(const half8*)(brow + cc * 8);
                acc[0] = __builtin_amdgcn_mfma_f32_16x16x32_f16(afrag[0][dk], bf, acc[0], 0, 0, 0);
                acc[1] = __builtin_amdgcn_mfma_f32_16x16x32_f16(afrag[1][dk], bf, acc[1], 0, 0, 0);
                acc[2] = __builtin_amdgcn_mfma_f32_16x16x32_f16(afrag[2][dk], bf, acc[2], 0, 0, 0);
                acc[3] = __builtin_amdgcn_mfma_f32_16x16x32_f16(afrag[3][dk], bf, acc[3], 0, 0, 0);
            }
            const int code = codeBase + ct * 16 + mcol;
            const float cn = cnv[ct];
            #pragma unroll
            for (int rt = 0; rt < 4; rt++)
                #pragma unroll
                for (int r = 0; r < 4; r++) {
                    float v = fmaf(-2.0f, acc[rt][r], cn);
                    if (v < bd0[rt][r]) {
                        bd1[rt][r] = bd0[rt][r]; bi1[rt][r] = bi0[rt][r];
                        bd0[rt][r] = v;          bi0[rt][r] = code;
                    } else if (v < bd1[rt][r]) {
                        bd1[rt][r] = v;          bi1[rt][r] = code;
                    }
                }
        }
        __syncthreads();
    }

    // ---- merge top-2 across the 16 class lanes (same-quad lanes hold the
    // same 16 tokens), then lane mcol==0 writes top-2 per (token, slice).
    #pragma unroll
    for (int s = 1; s < 16; s <<= 1) {
        #pragma unroll
        for (int rt = 0; rt < 4; rt++)
            #pragma unroll
            for (int r = 0; r < 4; r++) {
                float od0 = __shfl_xor(bd0[rt][r], s, 64);
                int   oi0 = __shfl_xor(bi0[rt][r], s, 64);
                float od1 = __shfl_xor(bd1[rt][r], s, 64);
                int   oi1 = __shfl_xor(bi1[rt][r], s, 64);
                float a0 = bd0[rt][r], a1 = bd1[rt][r];
                int   y0 = bi0[rt][r], y1 = bi1[rt][r];
                bool ofirst = (od0 < a0) || (od0 == a0 && oi0 < y0);
                if (ofirst) {
                    bool t = (a0 < od1) || (a0 == od1 && y0 < oi1);
                    bd0[rt][r] = od0;            bi0[rt][r] = oi0;
                    bd1[rt][r] = t ? a0 : od1;   bi1[rt][r] = t ? y0 : oi1;
                } else {
                    bool t = (od0 < a1) || (od0 == a1 && oi0 < y1);
                    bd1[rt][r] = t ? od0 : a1;   bi1[rt][r] = t ? oi0 : y1;
                }
            }
    }
    if (mcol == 0) {
        #pragma unroll
        for (int rt = 0; rt < 4; rt++)
            #pragma unroll
            for (int r = 0; r < 4; r++) {
                int token = tokBase + rt * 16 + quad * 4 + r;
                size_t base = (size_t)token * (SLICES * 2) + blockIdx.y * 2;
                cand_i[base]     = bi0[rt][r];
                cand_i[base + 1] = bi1[rt][r];
            }
    }
}

// ---------------------------------------------------------------------------
// K2: exact fp32 re-score of 8 candidates/token (8 lanes per candidate, all
// in parallel), gather winner row, accumulate commitment loss.
__global__ __launch_bounds__(256) void finalize_kernel(
    const float* __restrict__ x, const float* __restrict__ cb,
    const float* __restrict__ cnorm, const int* __restrict__ cand_i,
    float* __restrict__ out) {

    const int tid = threadIdx.x, w = tid >> 6, lane = tid & 63;
    const int j = lane >> 3, sub = lane & 7;
    float lsum = 0.0f;

    #pragma unroll 1
    for (int i = 0; i < 16; i++) {
        const int token = blockIdx.x * 64 + w * 16 + i;
        const float* xrow = x + (size_t)token * DDIM;
        int cidx = cand_i[(size_t)token * 8 + j];
        const float* crow = cb + (size_t)cidx * DDIM;
        float p = 0.0f;
        #pragma unroll
        for (int c = 0; c < 8; c++) {
            f32x4 xa = *(const f32x4*)(xrow + sub * 32 + c * 4);
            f32x4 ca = *(const f32x4*)(crow + sub * 32 + c * 4);
            p += xa[0]*ca[0] + xa[1]*ca[1] + xa[2]*ca[2] + xa[3]*ca[3];
        }
        p += __shfl_xor(p, 1, 64);
        p += __shfl_xor(p, 2, 64);
        p += __shfl_xor(p, 4, 64);                   // dist partial per 8-lane group
        float bd = cnorm[cidx] - 2.0f * p;
        int   bidx = cidx;
        #pragma unroll
        for (int s = 8; s < 64; s <<= 1) {
            float od = __shfl_xor(bd, s, 64);
            int   oi = __shfl_xor(bidx, s, 64);
            if (od < bd || (od == bd && oi < bidx)) { bd = od; bidx = oi; }
        }
        f32x4 cv = *(const f32x4*)(cb + (size_t)bidx * DDIM + lane * 4);
        f32x4 xv = *(const f32x4*)(xrow + lane * 4);
        *(f32x4*)(out + (size_t)token * DDIM + lane * 4) = cv;
        float d0 = cv[0]-xv[0], d1 = cv[1]-xv[1], d2 = cv[2]-xv[2], d3 = cv[3]-xv[3];
        lsum += d0*d0 + d1*d1 + d2*d2 + d3*d3;
    }

    __shared__ float red[256];
    red[tid] = lsum;
    __syncthreads();
    #pragma unroll
    for (int s = 128; s > 0; s >>= 1) {
        if (tid < s) red[tid] += red[tid + s];
        __syncthreads();
    }
    if (tid == 0)
        atomicAdd(out + (size_t)N_TOK * DDIM,
                  red[0] * (0.25f / (float)((size_t)N_TOK * DDIM)));
}

// ---------------------------------------------------------------------------
extern "C" void kernel_launch(void* const* d_in, const int* in_sizes, int n_in,
                              void* d_out, int out_size, void* d_ws, size_t ws_size,
                              hipStream_t stream) {
    const float* x  = (const float*)d_in[0];
    const float* cb = (const float*)d_in[1];
    float* out = (float*)d_out;

    // ws: cb16 (4 MB f16) | cnorm[8192] f32 | cand_i[32768*8] int  (~5.3 MB)
    half_t* cb16  = (half_t*)d_ws;
    float*  cnorm = (float*)(cb16 + (size_t)KCB * DDIM);
    int*    cand_i = (int*)(cnorm + KCB);

    prep_cb<<<KCB, 64, 0, stream>>>(cb, cb16, cnorm, out);
    dim3 gA(N_TOK / 256, SLICES);
    passA<<<gA, 256, 0, stream>>>(x, cb16, cnorm, cand_i);
    finalize_kernel<<<N_TOK / 64, 256, 0, stream>>>(x, cb, cnorm, cand_i, out);
}

// Round 4
// 364.991 us; speedup vs baseline: 5.9630x; 1.2463x over previous
//
#include <hip/hip_runtime.h>
#include <math.h>

// x: (64,512,256) f32 -> 32768 tokens x 256 dims. codebook: (8192,256) f32.
#define N_TOK 32768
#define DDIM  256
#define KCB   8192
#define SLICES 4
#define KS     (KCB / SLICES)    // 2048 codes per slice
#define TCODES 32                // codes per LDS tile
#define NSTEP  (KS / TCODES)     // 64 tiles per slice

typedef _Float16 half_t;
typedef half_t half8 __attribute__((ext_vector_type(8)));
typedef half_t half4 __attribute__((ext_vector_type(4)));
typedef float  f32x4 __attribute__((ext_vector_type(4)));

#define GLOBAL_AS __attribute__((address_space(1)))
#define LDS_AS    __attribute__((address_space(3)))

// ---------------------------------------------------------------------------
// P0: codebook f32 -> f16 copy + fp32 row norms; block 0 zeroes loss slot.
__global__ __launch_bounds__(64) void prep_cb(const float* __restrict__ cb,
                                              half_t* __restrict__ cb16,
                                              float* __restrict__ cnorm,
                                              float* __restrict__ out) {
    int code = blockIdx.x;
    int lane = threadIdx.x;
    f32x4 v = *(const f32x4*)(cb + (size_t)code * DDIM + lane * 4);
    half4 h; h[0]=(half_t)v[0]; h[1]=(half_t)v[1]; h[2]=(half_t)v[2]; h[3]=(half_t)v[3];
    *(half4*)(cb16 + (size_t)code * DDIM + lane * 4) = h;
    float s = v[0]*v[0] + v[1]*v[1] + v[2]*v[2] + v[3]*v[3];
    #pragma unroll
    for (int off = 32; off > 0; off >>= 1) s += __shfl_down(s, off);
    if (lane == 0) cnorm[code] = s;
    if (code == 0 && lane == 0) out[(size_t)N_TOK * DDIM] = 0.0f;
}

// load 8 consecutive f32, convert to 8 f16 (prologue only)
__device__ __forceinline__ half8 ldcvt8(const float* __restrict__ p) {
    f32x4 a = *(const f32x4*)p;
    f32x4 b = *(const f32x4*)(p + 4);
    half8 h;
    h[0]=(half_t)a[0]; h[1]=(half_t)a[1]; h[2]=(half_t)a[2]; h[3]=(half_t)a[3];
    h[4]=(half_t)b[0]; h[5]=(half_t)b[1]; h[6]=(half_t)b[2]; h[7]=(half_t)b[3];
    return h;
}

// ---------------------------------------------------------------------------
// Pass A: 256 threads (4 waves), 128 tokens/block (32/wave), one 2048-code
// K-slice. 16x16x32 f16 MFMA; A fragments in regs (64 VGPRs — fits the
// 128-VGPR / 4-waves-per-EU budget, no spill); B staged from pre-converted
// f16 codebook via async global_load_lds, 32-code tiles, double-buffered.
__global__ __launch_bounds__(256, 4)
void passA(const float* __restrict__ x, const half_t* __restrict__ cb16,
           const float* __restrict__ cnorm, int* __restrict__ cand_i) {

    __shared__ __align__(16) half_t buf[2][TCODES * 256];   // 2 x 16 KB

    const int tid  = threadIdx.x;
    const int w    = tid >> 6;
    const int lane = tid & 63;
    const int quad = lane >> 4;
    const int mcol = lane & 15;
    const int tokBase   = blockIdx.x * 128 + w * 32;   // wave's 32 tokens
    const int codeBase0 = blockIdx.y * KS;

    // ---- A fragments: A[m=mcol][k=quad*8+j], full D=256 in regs (64 VGPRs)
    half8 afrag[2][8];
    #pragma unroll
    for (int rt = 0; rt < 2; rt++) {
        const float* xr = x + (size_t)(tokBase + rt * 16 + mcol) * DDIM + quad * 8;
        #pragma unroll
        for (int dk = 0; dk < 8; dk++)
            afrag[rt][dk] = ldcvt8(xr + dk * 32);
    }

    // ---- B-read LDS offsets (halves) within a ct row-block:
    // row = mcol, swizzled chunk cc = (dk*4+quad) ^ (mcol&7)
    int boff[8];
    #pragma unroll
    for (int dk = 0; dk < 8; dk++)
        boff[dk] = mcol * 256 + (((dk * 4 + quad) ^ (mcol & 7)) * 8);

    float bd0[2][4], bd1[2][4];
    int   bi0[2][4], bi1[2][4];
    #pragma unroll
    for (int rt = 0; rt < 2; rt++)
        #pragma unroll
        for (int r = 0; r < 4; r++) {
            bd0[rt][r] = INFINITY; bd1[rt][r] = INFINITY;
            bi0[rt][r] = 0;        bi1[rt][r] = 0;
        }

    // stage 16 KB tile nt into buffer b: 1024 x 16B chunks, 4/thread.
    // dest chunk = o*256 + w*64 + lane (wave-uniform base + lane*16);
    // source chunk c within row r is XOR-swizzled to match the read side.
    const char* cbbase = (const char*)(cb16 + (size_t)codeBase0 * DDIM);
    #define STAGE(nt, b)                                                        \
        {                                                                       \
            const char* srcb = cbbase + (size_t)(nt) * (TCODES * 512);          \
            _Pragma("unroll")                                                   \
            for (int o = 0; o < 4; o++) {                                       \
                int L = o * 256 + tid;                                          \
                int r = L >> 5, c = (L & 31) ^ (r & 7);                         \
                __builtin_amdgcn_global_load_lds(                               \
                    (const GLOBAL_AS void*)(srcb + r * 512 + c * 16),           \
                    (LDS_AS void*)&buf[b][(o * 256 + w * 64) * 8], 16, 0, 0);   \
            }                                                                   \
        }

    STAGE(0, 0)
    __syncthreads();

    for (int nt = 0; nt < NSTEP; nt++) {
        if (nt + 1 < NSTEP) STAGE(nt + 1, (nt + 1) & 1)

        const half_t* cur = buf[nt & 1];
        const int codeBase = codeBase0 + nt * TCODES;
        float cnv0 = cnorm[codeBase + mcol];
        float cnv1 = cnorm[codeBase + 16 + mcol];

        #pragma unroll
        for (int ct = 0; ct < 2; ct++) {
            const half_t* crow = cur + ct * 16 * 256;
            f32x4 acc[2] = {};
            #pragma unroll
            for (int dk = 0; dk < 8; dk++) {
                half8 bf = *(const half8*)(crow + boff[dk]);
                acc[0] = __builtin_amdgcn_mfma_f32_16x16x32_f16(afrag[0][dk], bf, acc[0], 0, 0, 0);
                acc[1] = __builtin_amdgcn_mfma_f32_16x16x32_f16(afrag[1][dk], bf, acc[1], 0, 0, 0);
            }
            // C layout: col = lane&15 (code), row = quad*4 + reg (token)
            const int   code = codeBase + ct * 16 + mcol;
            const float cn   = ct ? cnv1 : cnv0;
            #pragma unroll
            for (int rt = 0; rt < 2; rt++)
                #pragma unroll
                for (int r = 0; r < 4; r++) {
                    float v = fmaf(-2.0f, acc[rt][r], cn);
                    if (v < bd0[rt][r]) {
                        bd1[rt][r] = bd0[rt][r]; bi1[rt][r] = bi0[rt][r];
                        bd0[rt][r] = v;          bi0[rt][r] = code;
                    } else if (v < bd1[rt][r]) {
                        bd1[rt][r] = v;          bi1[rt][r] = code;
                    }
                }
        }
        __syncthreads();
    }

    // ---- merge top-2 across the 16 class lanes (same-quad lanes hold the
    // same 16 tokens), then lane mcol==0 writes top-2 per (token, slice).
    #pragma unroll
    for (int s = 1; s < 16; s <<= 1) {
        #pragma unroll
        for (int rt = 0; rt < 2; rt++)
            #pragma unroll
            for (int r = 0; r < 4; r++) {
                float od0 = __shfl_xor(bd0[rt][r], s, 64);
                int   oi0 = __shfl_xor(bi0[rt][r], s, 64);
                float od1 = __shfl_xor(bd1[rt][r], s, 64);
                int   oi1 = __shfl_xor(bi1[rt][r], s, 64);
                float a0 = bd0[rt][r], a1 = bd1[rt][r];
                int   y0 = bi0[rt][r], y1 = bi1[rt][r];
                bool ofirst = (od0 < a0) || (od0 == a0 && oi0 < y0);
                if (ofirst) {
                    bool t = (a0 < od1) || (a0 == od1 && y0 < oi1);
                    bd0[rt][r] = od0;            bi0[rt][r] = oi0;
                    bd1[rt][r] = t ? a0 : od1;   bi1[rt][r] = t ? y0 : oi1;
                } else {
                    bool t = (od0 < a1) || (od0 == a1 && oi0 < y1);
                    bd1[rt][r] = t ? od0 : a1;   bi1[rt][r] = t ? oi0 : y1;
                }
            }
    }
    if (mcol == 0) {
        #pragma unroll
        for (int rt = 0; rt < 2; rt++)
            #pragma unroll
            for (int r = 0; r < 4; r++) {
                int token = tokBase + rt * 16 + quad * 4 + r;
                size_t base = (size_t)token * (SLICES * 2) + blockIdx.y * 2;
                cand_i[base]     = bi0[rt][r];
                cand_i[base + 1] = bi1[rt][r];
            }
    }
}

// ---------------------------------------------------------------------------
// K2: exact fp32 re-score of 8 candidates/token (8 lanes per candidate, all
// in parallel); 4 tokens per wave (short serial chain), 2048 blocks.
__global__ __launch_bounds__(256) void finalize_kernel(
    const float* __restrict__ x, const float* __restrict__ cb,
    const float* __restrict__ cnorm, const int* __restrict__ cand_i,
    float* __restrict__ out) {

    const int tid = threadIdx.x, w = tid >> 6, lane = tid & 63;
    const int j = lane >> 3, sub = lane & 7;
    float lsum = 0.0f;

    #pragma unroll 1
    for (int i = 0; i < 4; i++) {
        const int token = blockIdx.x * 16 + w * 4 + i;
        const float* xrow = x + (size_t)token * DDIM;
        int cidx = cand_i[(size_t)token * 8 + j];
        const float* crow = cb + (size_t)cidx * DDIM;
        float p = 0.0f;
        #pragma unroll
        for (int c = 0; c < 8; c++) {
            f32x4 xa = *(const f32x4*)(xrow + sub * 32 + c * 4);
            f32x4 ca = *(const f32x4*)(crow + sub * 32 + c * 4);
            p += xa[0]*ca[0] + xa[1]*ca[1] + xa[2]*ca[2] + xa[3]*ca[3];
        }
        p += __shfl_xor(p, 1, 64);
        p += __shfl_xor(p, 2, 64);
        p += __shfl_xor(p, 4, 64);                   // dot per 8-lane group
        float bd = cnorm[cidx] - 2.0f * p;
        int   bidx = cidx;
        #pragma unroll
        for (int s = 8; s < 64; s <<= 1) {
            float od = __shfl_xor(bd, s, 64);
            int   oi = __shfl_xor(bidx, s, 64);
            if (od < bd || (od == bd && oi < bidx)) { bd = od; bidx = oi; }
        }
        f32x4 cv = *(const f32x4*)(cb + (size_t)bidx * DDIM + lane * 4);
        f32x4 xv = *(const f32x4*)(xrow + lane * 4);
        *(f32x4*)(out + (size_t)token * DDIM + lane * 4) = cv;
        float d0 = cv[0]-xv[0], d1 = cv[1]-xv[1], d2 = cv[2]-xv[2], d3 = cv[3]-xv[3];
        lsum += d0*d0 + d1*d1 + d2*d2 + d3*d3;
    }

    __shared__ float red[256];
    red[tid] = lsum;
    __syncthreads();
    #pragma unroll
    for (int s = 128; s > 0; s >>= 1) {
        if (tid < s) red[tid] += red[tid + s];
        __syncthreads();
    }
    if (tid == 0)
        atomicAdd(out + (size_t)N_TOK * DDIM,
                  red[0] * (0.25f / (float)((size_t)N_TOK * DDIM)));
}

// ---------------------------------------------------------------------------
extern "C" void kernel_launch(void* const* d_in, const int* in_sizes, int n_in,
                              void* d_out, int out_size, void* d_ws, size_t ws_size,
                              hipStream_t stream) {
    const float* x  = (const float*)d_in[0];
    const float* cb = (const float*)d_in[1];
    float* out = (float*)d_out;

    // ws: cb16 (4 MB f16) | cnorm[8192] f32 | cand_i[32768*8] int  (~5.3 MB)
    half_t* cb16   = (half_t*)d_ws;
    float*  cnorm  = (float*)(cb16 + (size_t)KCB * DDIM);
    int*    cand_i = (int*)(cnorm + KCB);

    prep_cb<<<KCB, 64, 0, stream>>>(cb, cb16, cnorm, out);
    dim3 gA(N_TOK / 128, SLICES);
    passA<<<gA, 256, 0, stream>>>(x, cb16, cnorm, cand_i);
    finalize_kernel<<<N_TOK / 16, 256, 0, stream>>>(x, cb, cnorm, cand_i, out);
}

// Round 5
// 349.869 us; speedup vs baseline: 6.2207x; 1.0432x over previous
//
#include <hip/hip_runtime.h>
#include <math.h>

// x: (64,512,256) f32 -> 32768 tokens x 256 dims. codebook: (8192,256) f32.
#define N_TOK 32768
#define DDIM  256
#define KCB   8192
#define SLICES 4
#define KS     (KCB / SLICES)    // 2048 codes per slice
#define TCODES 32                // codes per LDS tile
#define NSTEP  (KS / TCODES)     // 64 tiles per slice

typedef _Float16 half_t;
typedef half_t half8 __attribute__((ext_vector_type(8)));
typedef half_t half4 __attribute__((ext_vector_type(4)));
typedef float  f32x4 __attribute__((ext_vector_type(4)));
typedef float  f32x2 __attribute__((ext_vector_type(2)));

#define GLOBAL_AS __attribute__((address_space(1)))
#define LDS_AS    __attribute__((address_space(3)))

// ---------------------------------------------------------------------------
// P0: codebook f32 -> f16 copy + fp32 row norms; block 0 zeroes loss slot.
__global__ __launch_bounds__(64) void prep_cb(const float* __restrict__ cb,
                                              half_t* __restrict__ cb16,
                                              float* __restrict__ cnorm,
                                              float* __restrict__ out) {
    int code = blockIdx.x;
    int lane = threadIdx.x;
    f32x4 v = *(const f32x4*)(cb + (size_t)code * DDIM + lane * 4);
    half4 h; h[0]=(half_t)v[0]; h[1]=(half_t)v[1]; h[2]=(half_t)v[2]; h[3]=(half_t)v[3];
    *(half4*)(cb16 + (size_t)code * DDIM + lane * 4) = h;
    float s = v[0]*v[0] + v[1]*v[1] + v[2]*v[2] + v[3]*v[3];
    #pragma unroll
    for (int off = 32; off > 0; off >>= 1) s += __shfl_down(s, off);
    if (lane == 0) cnorm[code] = s;
    if (code == 0 && lane == 0) out[(size_t)N_TOK * DDIM] = 0.0f;
}

// load 8 consecutive f32, convert to 8 f16 (prologue only)
__device__ __forceinline__ half8 ldcvt8(const float* __restrict__ p) {
    f32x4 a = *(const f32x4*)p;
    f32x4 b = *(const f32x4*)(p + 4);
    half8 h;
    h[0]=(half_t)a[0]; h[1]=(half_t)a[1]; h[2]=(half_t)a[2]; h[3]=(half_t)a[3];
    h[4]=(half_t)b[0]; h[5]=(half_t)b[1]; h[6]=(half_t)b[2]; h[7]=(half_t)b[3];
    return h;
}

// ---------------------------------------------------------------------------
// Pass A: 256 threads (4 waves), 128 tokens/block (32/wave), one 2048-code
// K-slice. 16x16x32 f16 MFMA; A fragments in regs/AGPRs; B staged via async
// global_load_lds, 32-code tiles, double-buffered. Top-2 per (token, slice)
// tracked as packed sortable keys: f32 distance with low 13 mantissa bits
// replaced by the global code index (<=2^-10 relative perturbation; exact
// re-score happens in finalize). Update = pure min/max, no cndmask chains.
__global__ __launch_bounds__(256, 4)
void passA(const float* __restrict__ x, const half_t* __restrict__ cb16,
           const float* __restrict__ cnorm, float* __restrict__ cand) {

    __shared__ __align__(16) half_t buf[2][TCODES * 256];   // 2 x 16 KB

    const int tid  = threadIdx.x;
    const int w    = tid >> 6;
    const int lane = tid & 63;
    const int quad = lane >> 4;
    const int mcol = lane & 15;
    const int tokBase   = blockIdx.x * 128 + w * 32;   // wave's 32 tokens
    const int codeBase0 = blockIdx.y * KS;

    // ---- A fragments: A[m=mcol][k=quad*8+j], full D=256 in regs (64 regs)
    half8 afrag[2][8];
    #pragma unroll
    for (int rt = 0; rt < 2; rt++) {
        const float* xr = x + (size_t)(tokBase + rt * 16 + mcol) * DDIM + quad * 8;
        #pragma unroll
        for (int dk = 0; dk < 8; dk++)
            afrag[rt][dk] = ldcvt8(xr + dk * 32);
    }

    // ---- B-read LDS offsets (halves): row = mcol, chunk = (dk*4+quad)^(mcol&7)
    int boff[8];
    #pragma unroll
    for (int dk = 0; dk < 8; dk++)
        boff[dk] = mcol * 256 + (((dk * 4 + quad) ^ (mcol & 7)) * 8);

    // packed top-2 keys per owned token [rt][r]
    float k0[2][4], k1[2][4];
    #pragma unroll
    for (int rt = 0; rt < 2; rt++)
        #pragma unroll
        for (int r = 0; r < 4; r++) { k0[rt][r] = INFINITY; k1[rt][r] = INFINITY; }

    // stage 16 KB tile nt into buffer b (async, swizzled to match read side)
    const char* cbbase = (const char*)(cb16 + (size_t)codeBase0 * DDIM);
    #define STAGE(nt, b)                                                        \
        {                                                                       \
            const char* srcb = cbbase + (size_t)(nt) * (TCODES * 512);          \
            _Pragma("unroll")                                                   \
            for (int o = 0; o < 4; o++) {                                       \
                int L = o * 256 + tid;                                          \
                int r = L >> 5, c = (L & 31) ^ (r & 7);                         \
                __builtin_amdgcn_global_load_lds(                               \
                    (const GLOBAL_AS void*)(srcb + r * 512 + c * 16),           \
                    (LDS_AS void*)&buf[b][(o * 256 + w * 64) * 8], 16, 0, 0);   \
            }                                                                   \
        }

    STAGE(0, 0)
    __syncthreads();

    for (int nt = 0; nt < NSTEP; nt++) {
        if (nt + 1 < NSTEP) STAGE(nt + 1, (nt + 1) & 1)

        const half_t* cur = buf[nt & 1];
        const int codeBase = codeBase0 + nt * TCODES;
        float cnv0 = cnorm[codeBase + mcol];
        float cnv1 = cnorm[codeBase + 16 + mcol];

        #pragma unroll
        for (int ct = 0; ct < 2; ct++) {
            const half_t* crow = cur + ct * 16 * 256;
            f32x4 acc[2] = {};
            #pragma unroll
            for (int dk = 0; dk < 8; dk++) {
                half8 bf = *(const half8*)(crow + boff[dk]);
                acc[0] = __builtin_amdgcn_mfma_f32_16x16x32_f16(afrag[0][dk], bf, acc[0], 0, 0, 0);
                acc[1] = __builtin_amdgcn_mfma_f32_16x16x32_f16(afrag[1][dk], bf, acc[1], 0, 0, 0);
            }
            // C layout: col = lane&15 (code), row = quad*4 + reg (token)
            const unsigned code = (unsigned)(codeBase + ct * 16 + mcol);
            const float cn = ct ? cnv1 : cnv0;
            #pragma unroll
            for (int rt = 0; rt < 2; rt++)
                #pragma unroll
                for (int r = 0; r < 4; r++) {
                    float d = fmaf(-2.0f, acc[rt][r], cn);
                    float kf = __uint_as_float((__float_as_uint(d) & 0xFFFFE000u) | code);
                    float km = fmaxf(k0[rt][r], kf);
                    k0[rt][r] = fminf(k0[rt][r], kf);
                    k1[rt][r] = fminf(k1[rt][r], km);
                }
        }
        __syncthreads();
    }

    // ---- merge top-2 across the 16 class lanes (same-quad lanes hold the
    // same 16 tokens): pairwise merge of sorted pairs, 4 butterfly steps.
    #pragma unroll
    for (int s = 1; s < 16; s <<= 1) {
        #pragma unroll
        for (int rt = 0; rt < 2; rt++)
            #pragma unroll
            for (int r = 0; r < 4; r++) {
                float o0 = __shfl_xor(k0[rt][r], s, 64);
                float o1 = __shfl_xor(k1[rt][r], s, 64);
                float n1 = fminf(fmaxf(k0[rt][r], o0), fminf(k1[rt][r], o1));
                k0[rt][r] = fminf(k0[rt][r], o0);
                k1[rt][r] = n1;
            }
    }
    if (mcol == 0) {
        #pragma unroll
        for (int rt = 0; rt < 2; rt++)
            #pragma unroll
            for (int r = 0; r < 4; r++) {
                int token = tokBase + rt * 16 + quad * 4 + r;
                f32x2 kk; kk[0] = k0[rt][r]; kk[1] = k1[rt][r];
                *(f32x2*)&cand[(size_t)token * (SLICES * 2) + blockIdx.y * 2] = kk;
            }
    }
}

// ---------------------------------------------------------------------------
// K2: exact fp32 re-score of 8 candidates/token; 1 token per wave (8 lanes
// per candidate, all 8 in parallel), gather winner row, accumulate loss.
__global__ __launch_bounds__(256) void finalize_kernel(
    const float* __restrict__ x, const float* __restrict__ cb,
    const float* __restrict__ cnorm, const float* __restrict__ cand,
    float* __restrict__ out) {

    const int tid = threadIdx.x, w = tid >> 6, lane = tid & 63;
    const int j = lane >> 3, sub = lane & 7;
    const int token = blockIdx.x * 4 + w;

    const float* xrow = x + (size_t)token * DDIM;
    unsigned cidx = __float_as_uint(cand[(size_t)token * 8 + j]) & 0x1FFFu;
    const float* crow = cb + (size_t)cidx * DDIM;
    float p = 0.0f;
    #pragma unroll
    for (int c = 0; c < 8; c++) {
        f32x4 xa = *(const f32x4*)(xrow + sub * 32 + c * 4);
        f32x4 ca = *(const f32x4*)(crow + sub * 32 + c * 4);
        p += xa[0]*ca[0] + xa[1]*ca[1] + xa[2]*ca[2] + xa[3]*ca[3];
    }
    p += __shfl_xor(p, 1, 64);
    p += __shfl_xor(p, 2, 64);
    p += __shfl_xor(p, 4, 64);                   // exact dot per 8-lane group
    float bd = cnorm[cidx] - 2.0f * p;
    int   bidx = (int)cidx;
    #pragma unroll
    for (int s = 8; s < 64; s <<= 1) {
        float od = __shfl_xor(bd, s, 64);
        int   oi = __shfl_xor(bidx, s, 64);
        if (od < bd || (od == bd && oi < bidx)) { bd = od; bidx = oi; }
    }
    f32x4 cv = *(const f32x4*)(cb + (size_t)bidx * DDIM + lane * 4);
    f32x4 xv = *(const f32x4*)(xrow + lane * 4);
    *(f32x4*)(out + (size_t)token * DDIM + lane * 4) = cv;
    float d0 = cv[0]-xv[0], d1 = cv[1]-xv[1], d2 = cv[2]-xv[2], d3 = cv[3]-xv[3];
    float lsum = d0*d0 + d1*d1 + d2*d2 + d3*d3;

    __shared__ float red[256];
    red[tid] = lsum;
    __syncthreads();
    #pragma unroll
    for (int s = 128; s > 0; s >>= 1) {
        if (tid < s) red[tid] += red[tid + s];
        __syncthreads();
    }
    if (tid == 0)
        atomicAdd(out + (size_t)N_TOK * DDIM,
                  red[0] * (0.25f / (float)((size_t)N_TOK * DDIM)));
}

// ---------------------------------------------------------------------------
extern "C" void kernel_launch(void* const* d_in, const int* in_sizes, int n_in,
                              void* d_out, int out_size, void* d_ws, size_t ws_size,
                              hipStream_t stream) {
    const float* x  = (const float*)d_in[0];
    const float* cb = (const float*)d_in[1];
    float* out = (float*)d_out;

    // ws: cb16 (4 MB f16) | cnorm[8192] f32 | cand[32768*8] f32  (~5.3 MB)
    half_t* cb16  = (half_t*)d_ws;
    float*  cnorm = (float*)(cb16 + (size_t)KCB * DDIM);
    float*  cand  = cnorm + KCB;

    prep_cb<<<KCB, 64, 0, stream>>>(cb, cb16, cnorm, out);
    dim3 gA(N_TOK / 128, SLICES);
    passA<<<gA, 256, 0, stream>>>(x, cb16, cnorm, cand);
    finalize_kernel<<<N_TOK / 4, 256, 0, stream>>>(x, cb, cnorm, cand, out);
}

// Round 6
// 341.427 us; speedup vs baseline: 6.3745x; 1.0247x over previous
//
#include <hip/hip_runtime.h>
#include <math.h>

// x: (64,512,256) f32 -> 32768 tokens x 256 dims. codebook: (8192,256) f32.
#define N_TOK 32768
#define DDIM  256
#define KCB   8192
#define SLICES 4
#define KS     (KCB / SLICES)    // 2048 codes per slice
#define TCODES 32                // codes per LDS tile
#define NSTEP  (KS / TCODES)     // 64 tiles per slice
#define MARGIN 1.0f              // acc-scale gap guaranteeing exact winner

typedef _Float16 half_t;
typedef half_t half8 __attribute__((ext_vector_type(8)));
typedef half_t half4 __attribute__((ext_vector_type(4)));
typedef float  f32x4 __attribute__((ext_vector_type(4)));
typedef float  f32x2 __attribute__((ext_vector_type(2)));

#define GLOBAL_AS __attribute__((address_space(1)))
#define LDS_AS    __attribute__((address_space(3)))

// ---------------------------------------------------------------------------
// P0: codebook f32 -> f16 copy + fp32 row norms; block 0 zeroes loss slot.
__global__ __launch_bounds__(64) void prep_cb(const float* __restrict__ cb,
                                              half_t* __restrict__ cb16,
                                              float* __restrict__ cnorm,
                                              float* __restrict__ out) {
    int code = blockIdx.x;
    int lane = threadIdx.x;
    f32x4 v = *(const f32x4*)(cb + (size_t)code * DDIM + lane * 4);
    half4 h; h[0]=(half_t)v[0]; h[1]=(half_t)v[1]; h[2]=(half_t)v[2]; h[3]=(half_t)v[3];
    *(half4*)(cb16 + (size_t)code * DDIM + lane * 4) = h;
    float s = v[0]*v[0] + v[1]*v[1] + v[2]*v[2] + v[3]*v[3];
    #pragma unroll
    for (int off = 32; off > 0; off >>= 1) s += __shfl_down(s, off);
    if (lane == 0) cnorm[code] = s;
    if (code == 0 && lane == 0) out[(size_t)N_TOK * DDIM] = 0.0f;
}

// load 8 consecutive f32, convert to 8 f16 (prologue only)
__device__ __forceinline__ half8 ldcvt8(const float* __restrict__ p) {
    f32x4 a = *(const f32x4*)p;
    f32x4 b = *(const f32x4*)(p + 4);
    half8 h;
    h[0]=(half_t)a[0]; h[1]=(half_t)a[1]; h[2]=(half_t)a[2]; h[3]=(half_t)a[3];
    h[4]=(half_t)b[0]; h[5]=(half_t)b[1]; h[6]=(half_t)b[2]; h[7]=(half_t)b[3];
    return h;
}

// ---------------------------------------------------------------------------
// Pass A: 256 threads (4 waves), 128 tokens/block (32/wave), one 2048-code
// K-slice. 16x16x32 f16 MFMA. cnorm is folded into the MFMA accumulator
// (acc init = -cn/2, so acc_final = dot - cn/2 = -d/2): no per-distance fmaf.
// Top-2 tracked as MAX of packed sortable keys (acc with low 13 mantissa
// bits replaced by code id); exact fp32 re-score happens in finalize.
__global__ __launch_bounds__(256, 4)
void passA(const float* __restrict__ x, const half_t* __restrict__ cb16,
           const float* __restrict__ cnorm, float* __restrict__ cand) {

    __shared__ __align__(16) half_t buf[2][TCODES * 256];   // 2 x 16 KB

    const int tid  = threadIdx.x;
    const int w    = tid >> 6;
    const int lane = tid & 63;
    const int quad = lane >> 4;
    const int mcol = lane & 15;
    const int tokBase   = blockIdx.x * 128 + w * 32;   // wave's 32 tokens
    const int codeBase0 = blockIdx.y * KS;

    // ---- A fragments: A[m=mcol][k=quad*8+j], full D=256 in regs (64 regs)
    half8 afrag[2][8];
    #pragma unroll
    for (int rt = 0; rt < 2; rt++) {
        const float* xr = x + (size_t)(tokBase + rt * 16 + mcol) * DDIM + quad * 8;
        #pragma unroll
        for (int dk = 0; dk < 8; dk++)
            afrag[rt][dk] = ldcvt8(xr + dk * 32);
    }

    // ---- B-read LDS offsets (halves): row = mcol, chunk = (dk*4+quad)^(mcol&7)
    int boff[8];
    #pragma unroll
    for (int dk = 0; dk < 8; dk++)
        boff[dk] = mcol * 256 + (((dk * 4 + quad) ^ (mcol & 7)) * 8);

    // packed top-2 keys (max semantics) per owned token [rt][r]
    float k0[2][4], k1[2][4];
    #pragma unroll
    for (int rt = 0; rt < 2; rt++)
        #pragma unroll
        for (int r = 0; r < 4; r++) { k0[rt][r] = -INFINITY; k1[rt][r] = -INFINITY; }

    // stage 16 KB tile nt into buffer b (async, swizzled to match read side)
    const char* cbbase = (const char*)(cb16 + (size_t)codeBase0 * DDIM);
    #define STAGE(nt, b)                                                        \
        {                                                                       \
            const char* srcb = cbbase + (size_t)(nt) * (TCODES * 512);          \
            _Pragma("unroll")                                                   \
            for (int o = 0; o < 4; o++) {                                       \
                int L = o * 256 + tid;                                          \
                int r = L >> 5, c = (L & 31) ^ (r & 7);                         \
                __builtin_amdgcn_global_load_lds(                               \
                    (const GLOBAL_AS void*)(srcb + r * 512 + c * 16),           \
                    (LDS_AS void*)&buf[b][(o * 256 + w * 64) * 8], 16, 0, 0);   \
            }                                                                   \
        }

    STAGE(0, 0)
    __syncthreads();

    for (int nt = 0; nt < NSTEP; nt++) {
        if (nt + 1 < NSTEP) STAGE(nt + 1, (nt + 1) & 1)

        const half_t* cur = buf[nt & 1];
        const int codeBase = codeBase0 + nt * TCODES;
        float cnv0 = cnorm[codeBase + mcol];
        float cnv1 = cnorm[codeBase + 16 + mcol];

        #pragma unroll
        for (int ct = 0; ct < 2; ct++) {
            const half_t* crow = cur + ct * 16 * 256;
            const float mc = -0.5f * (ct ? cnv1 : cnv0);
            f32x4 acc[2];
            #pragma unroll
            for (int rt = 0; rt < 2; rt++) {
                acc[rt][0] = mc; acc[rt][1] = mc; acc[rt][2] = mc; acc[rt][3] = mc;
            }
            #pragma unroll
            for (int dk = 0; dk < 8; dk++) {
                half8 bf = *(const half8*)(crow + boff[dk]);
                acc[0] = __builtin_amdgcn_mfma_f32_16x16x32_f16(afrag[0][dk], bf, acc[0], 0, 0, 0);
                acc[1] = __builtin_amdgcn_mfma_f32_16x16x32_f16(afrag[1][dk], bf, acc[1], 0, 0, 0);
            }
            // C layout: col = lane&15 (code), row = quad*4 + reg (token)
            // key = acc (= dot - cn/2, monotone opposite of distance) with low
            // 13 mantissa bits replaced by the code id; track top-2 by max.
            const unsigned code = (unsigned)(codeBase + ct * 16 + mcol);
            #pragma unroll
            for (int rt = 0; rt < 2; rt++)
                #pragma unroll
                for (int r = 0; r < 4; r++) {
                    float kf = __uint_as_float((__float_as_uint(acc[rt][r]) & 0xFFFFE000u) | code);
                    float km = fminf(k0[rt][r], kf);
                    k0[rt][r] = fmaxf(k0[rt][r], kf);
                    k1[rt][r] = fmaxf(k1[rt][r], km);
                }
        }
        __syncthreads();
    }

    // ---- merge top-2 (max) across the 16 class lanes; lane mcol==0 writes.
    #pragma unroll
    for (int s = 1; s < 16; s <<= 1) {
        #pragma unroll
        for (int rt = 0; rt < 2; rt++)
            #pragma unroll
            for (int r = 0; r < 4; r++) {
                float o0 = __shfl_xor(k0[rt][r], s, 64);
                float o1 = __shfl_xor(k1[rt][r], s, 64);
                float n1 = fmaxf(fminf(k0[rt][r], o0), fmaxf(k1[rt][r], o1));
                k0[rt][r] = fmaxf(k0[rt][r], o0);
                k1[rt][r] = n1;
            }
    }
    if (mcol == 0) {
        #pragma unroll
        for (int rt = 0; rt < 2; rt++)
            #pragma unroll
            for (int r = 0; r < 4; r++) {
                int token = tokBase + rt * 16 + quad * 4 + r;
                f32x2 kk; kk[0] = k0[rt][r]; kk[1] = k1[rt][r];
                *(f32x2*)&cand[(size_t)token * (SLICES * 2) + blockIdx.y * 2] = kk;
            }
    }
}

// ---------------------------------------------------------------------------
// K2: 1 token/wave. Keys are max-sortable; if the best key beats the 2nd by
// > MARGIN (covers worst-case f16 + packing error of both candidates), the
// winner is certain -> gather 1 row. Else exact fp32 re-score of all 8.
__global__ __launch_bounds__(256) void finalize_kernel(
    const float* __restrict__ x, const float* __restrict__ cb,
    const float* __restrict__ cnorm, const float* __restrict__ cand,
    float* __restrict__ out) {

    const int tid = threadIdx.x, w = tid >> 6, lane = tid & 63;
    const int token = blockIdx.x * 4 + w;
    const float* xrow = x + (size_t)token * DDIM;

    // all lanes: load the 8 keys (broadcast), top-2 by max
    f32x4 ka = *(const f32x4*)(cand + (size_t)token * 8);
    f32x4 kb = *(const f32x4*)(cand + (size_t)token * 8 + 4);
    float v[8] = {ka[0], ka[1], ka[2], ka[3], kb[0], kb[1], kb[2], kb[3]};
    float t0 = -INFINITY, t1 = -INFINITY;
    #pragma unroll
    for (int j = 0; j < 8; j++) {
        float m = fminf(t0, v[j]);
        t0 = fmaxf(t0, v[j]);
        t1 = fmaxf(t1, m);
    }
    int bidx = (int)(__float_as_uint(t0) & 0x1FFFu);

    if (!(t0 - t1 > MARGIN)) {
        // exact fp32 re-score of all 8 candidates (8 lanes per candidate)
        const int j = lane >> 3, sub = lane & 7;
        int cj = (int)(__float_as_uint(v[j]) & 0x1FFFu);
        const float* crow = cb + (size_t)cj * DDIM;
        float p = 0.0f;
        #pragma unroll
        for (int c = 0; c < 8; c++) {   // group lanes cover 32 contiguous floats
            f32x4 xa = *(const f32x4*)(xrow + c * 32 + sub * 4);
            f32x4 ca = *(const f32x4*)(crow + c * 32 + sub * 4);
            p += xa[0]*ca[0] + xa[1]*ca[1] + xa[2]*ca[2] + xa[3]*ca[3];
        }
        p += __shfl_xor(p, 1, 64);
        p += __shfl_xor(p, 2, 64);
        p += __shfl_xor(p, 4, 64);
        float bd = cnorm[cj] - 2.0f * p;
        int   bi = cj;
        #pragma unroll
        for (int s = 8; s < 64; s <<= 1) {   // reference tie-break: lower index
            float od = __shfl_xor(bd, s, 64);
            int   oi = __shfl_xor(bi, s, 64);
            if (od < bd || (od == bd && oi < bi)) { bd = od; bi = oi; }
        }
        bidx = bi;
    }

    // common tail: gather winner row, write out, commitment-loss partial
    f32x4 cv = *(const f32x4*)(cb + (size_t)bidx * DDIM + lane * 4);
    f32x4 xv = *(const f32x4*)(xrow + lane * 4);
    *(f32x4*)(out + (size_t)token * DDIM + lane * 4) = cv;
    float d0 = cv[0]-xv[0], d1 = cv[1]-xv[1], d2 = cv[2]-xv[2], d3 = cv[3]-xv[3];
    float lsum = d0*d0 + d1*d1 + d2*d2 + d3*d3;

    __shared__ float red[256];
    red[tid] = lsum;
    __syncthreads();
    #pragma unroll
    for (int s = 128; s > 0; s >>= 1) {
        if (tid < s) red[tid] += red[tid + s];
        __syncthreads();
    }
    if (tid == 0)
        atomicAdd(out + (size_t)N_TOK * DDIM,
                  red[0] * (0.25f / (float)((size_t)N_TOK * DDIM)));
}

// ---------------------------------------------------------------------------
extern "C" void kernel_launch(void* const* d_in, const int* in_sizes, int n_in,
                              void* d_out, int out_size, void* d_ws, size_t ws_size,
                              hipStream_t stream) {
    const float* x  = (const float*)d_in[0];
    const float* cb = (const float*)d_in[1];
    float* out = (float*)d_out;

    // ws: cb16 (4 MB f16) | cnorm[8192] f32 | cand[32768*8] f32  (~5.3 MB)
    half_t* cb16  = (half_t*)d_ws;
    float*  cnorm = (float*)(cb16 + (size_t)KCB * DDIM);
    float*  cand  = cnorm + KCB;

    prep_cb<<<KCB, 64, 0, stream>>>(cb, cb16, cnorm, out);
    dim3 gA(N_TOK / 128, SLICES);
    passA<<<gA, 256, 0, stream>>>(x, cb16, cnorm, cand);
    finalize_kernel<<<N_TOK / 4, 256, 0, stream>>>(x, cb, cnorm, cand, out);
}

// Round 7
// 243.445 us; speedup vs baseline: 8.9402x; 1.4025x over previous
//
#include <hip/hip_runtime.h>
#include <math.h>

// x: (64,512,256) f32 -> 32768 tokens x 256 dims. codebook: (8192,256) f32.
#define N_TOK 32768
#define DDIM  256
#define KCB   8192
#define SLICES 4
#define KS     (KCB / SLICES)    // 2048 codes per slice
#define TCODES 32                // codes per LDS tile
#define NSTEP  (KS / TCODES)     // 64 tiles per slice
#define MARGIN 1.0f              // acc-scale gap guaranteeing exact winner
#define NFBLK  (N_TOK / 4)       // finalize blocks (1 token/wave, 4 waves)

typedef _Float16 half_t;
typedef half_t half8 __attribute__((ext_vector_type(8)));
typedef half_t half4 __attribute__((ext_vector_type(4)));
typedef float  f32x4 __attribute__((ext_vector_type(4)));
typedef float  f32x2 __attribute__((ext_vector_type(2)));

#define GLOBAL_AS __attribute__((address_space(1)))
#define LDS_AS    __attribute__((address_space(3)))

// ---------------------------------------------------------------------------
// P0: codebook f32 -> f16 copy + fp32 row norms.
__global__ __launch_bounds__(64) void prep_cb(const float* __restrict__ cb,
                                              half_t* __restrict__ cb16,
                                              float* __restrict__ cnorm) {
    int code = blockIdx.x;
    int lane = threadIdx.x;
    f32x4 v = *(const f32x4*)(cb + (size_t)code * DDIM + lane * 4);
    half4 h; h[0]=(half_t)v[0]; h[1]=(half_t)v[1]; h[2]=(half_t)v[2]; h[3]=(half_t)v[3];
    *(half4*)(cb16 + (size_t)code * DDIM + lane * 4) = h;
    float s = v[0]*v[0] + v[1]*v[1] + v[2]*v[2] + v[3]*v[3];
    #pragma unroll
    for (int off = 32; off > 0; off >>= 1) s += __shfl_down(s, off);
    if (lane == 0) cnorm[code] = s;
}

// load 8 consecutive f32, convert to 8 f16 (prologue only)
__device__ __forceinline__ half8 ldcvt8(const float* __restrict__ p) {
    f32x4 a = *(const f32x4*)p;
    f32x4 b = *(const f32x4*)(p + 4);
    half8 h;
    h[0]=(half_t)a[0]; h[1]=(half_t)a[1]; h[2]=(half_t)a[2]; h[3]=(half_t)a[3];
    h[4]=(half_t)b[0]; h[5]=(half_t)b[1]; h[6]=(half_t)b[2]; h[7]=(half_t)b[3];
    return h;
}

// pack: f32 key with low 13 mantissa bits replaced by code id (sortable)
__device__ __forceinline__ float packkey(float a, unsigned code) {
    return __uint_as_float((__float_as_uint(a) & 0xFFFFE000u) | code);
}

// ---------------------------------------------------------------------------
// Pass A: 256 threads (4 waves), 128 tokens/block (32/wave), one 2048-code
// K-slice. 16x16x32 f16 MFMA; cnorm folded into the accumulator (acc init
// = -cn/2 so acc = dot - cn/2 = -d/2, monotone). Both 16-code column tiles
// computed first, then a 2-at-a-time exact top-2 update per token:
//   k1 = max(k1, med3(k0, a, b)); k0 = max3(k0, a, b)   (5-6 VALU / 2 dists)
__global__ __launch_bounds__(256, 4)
void passA(const float* __restrict__ x, const half_t* __restrict__ cb16,
           const float* __restrict__ cnorm, float* __restrict__ cand) {

    __shared__ __align__(16) half_t buf[2][TCODES * 256];   // 2 x 16 KB

    const int tid  = threadIdx.x;
    const int w    = tid >> 6;
    const int lane = tid & 63;
    const int quad = lane >> 4;
    const int mcol = lane & 15;
    const int tokBase   = blockIdx.x * 128 + w * 32;   // wave's 32 tokens
    const int codeBase0 = blockIdx.y * KS;

    // ---- A fragments: A[m=mcol][k=quad*8+j], full D=256 in regs (64 regs)
    half8 afrag[2][8];
    #pragma unroll
    for (int rt = 0; rt < 2; rt++) {
        const float* xr = x + (size_t)(tokBase + rt * 16 + mcol) * DDIM + quad * 8;
        #pragma unroll
        for (int dk = 0; dk < 8; dk++)
            afrag[rt][dk] = ldcvt8(xr + dk * 32);
    }

    // ---- B-read LDS offsets (halves): row = mcol, chunk = (dk*4+quad)^(mcol&7)
    int boff[8];
    #pragma unroll
    for (int dk = 0; dk < 8; dk++)
        boff[dk] = mcol * 256 + (((dk * 4 + quad) ^ (mcol & 7)) * 8);

    // packed top-2 keys (max semantics) per owned token [rt][r]
    float k0[2][4], k1[2][4];
    #pragma unroll
    for (int rt = 0; rt < 2; rt++)
        #pragma unroll
        for (int r = 0; r < 4; r++) { k0[rt][r] = -INFINITY; k1[rt][r] = -INFINITY; }

    // stage 16 KB tile nt into buffer b (async, swizzled to match read side)
    const char* cbbase = (const char*)(cb16 + (size_t)codeBase0 * DDIM);
    #define STAGE(nt, b)                                                        \
        {                                                                       \
            const char* srcb = cbbase + (size_t)(nt) * (TCODES * 512);          \
            _Pragma("unroll")                                                   \
            for (int o = 0; o < 4; o++) {                                       \
                int L = o * 256 + tid;                                          \
                int r = L >> 5, c = (L & 31) ^ (r & 7);                         \
                __builtin_amdgcn_global_load_lds(                               \
                    (const GLOBAL_AS void*)(srcb + r * 512 + c * 16),           \
                    (LDS_AS void*)&buf[b][(o * 256 + w * 64) * 8], 16, 0, 0);   \
            }                                                                   \
        }

    STAGE(0, 0)
    __syncthreads();

    for (int nt = 0; nt < NSTEP; nt++) {
        if (nt + 1 < NSTEP) STAGE(nt + 1, (nt + 1) & 1)

        const half_t* cur = buf[nt & 1];
        const int codeBase = codeBase0 + nt * TCODES;
        const float mc0 = -0.5f * cnorm[codeBase + mcol];
        const float mc1 = -0.5f * cnorm[codeBase + 16 + mcol];

        // both column tiles' accumulators, 4 independent MFMA chains
        f32x4 acc[2][2];
        #pragma unroll
        for (int rt = 0; rt < 2; rt++) {
            acc[0][rt][0]=mc0; acc[0][rt][1]=mc0; acc[0][rt][2]=mc0; acc[0][rt][3]=mc0;
            acc[1][rt][0]=mc1; acc[1][rt][1]=mc1; acc[1][rt][2]=mc1; acc[1][rt][3]=mc1;
        }
        const half_t* crow0 = cur;
        const half_t* crow1 = cur + 16 * 256;
        #pragma unroll
        for (int dk = 0; dk < 8; dk++) {
            half8 bf0 = *(const half8*)(crow0 + boff[dk]);
            half8 bf1 = *(const half8*)(crow1 + boff[dk]);
            acc[0][0] = __builtin_amdgcn_mfma_f32_16x16x32_f16(afrag[0][dk], bf0, acc[0][0], 0, 0, 0);
            acc[0][1] = __builtin_amdgcn_mfma_f32_16x16x32_f16(afrag[1][dk], bf0, acc[0][1], 0, 0, 0);
            acc[1][0] = __builtin_amdgcn_mfma_f32_16x16x32_f16(afrag[0][dk], bf1, acc[1][0], 0, 0, 0);
            acc[1][1] = __builtin_amdgcn_mfma_f32_16x16x32_f16(afrag[1][dk], bf1, acc[1][1], 0, 0, 0);
        }

        // C layout: col = lane&15 (code), row = quad*4 + r (token).
        // Per token: update top-2 with the two codes at once (exact).
        const unsigned code0 = (unsigned)(codeBase + mcol);
        const unsigned code1 = (unsigned)(codeBase + 16 + mcol);
        #pragma unroll
        for (int rt = 0; rt < 2; rt++)
            #pragma unroll
            for (int r = 0; r < 4; r++) {
                float a = packkey(acc[0][rt][r], code0);
                float b = packkey(acc[1][rt][r], code1);
                k1[rt][r] = fmaxf(k1[rt][r], __builtin_amdgcn_fmed3f(k0[rt][r], a, b));
                k0[rt][r] = fmaxf(fmaxf(k0[rt][r], a), b);
            }
        __syncthreads();
    }

    // ---- merge top-2 (max) across the 16 class lanes; lane mcol==0 writes.
    #pragma unroll
    for (int s = 1; s < 16; s <<= 1) {
        #pragma unroll
        for (int rt = 0; rt < 2; rt++)
            #pragma unroll
            for (int r = 0; r < 4; r++) {
                float o0 = __shfl_xor(k0[rt][r], s, 64);
                float o1 = __shfl_xor(k1[rt][r], s, 64);
                float n1 = fmaxf(fminf(k0[rt][r], o0), fmaxf(k1[rt][r], o1));
                k0[rt][r] = fmaxf(k0[rt][r], o0);
                k1[rt][r] = n1;
            }
    }
    if (mcol == 0) {
        #pragma unroll
        for (int rt = 0; rt < 2; rt++)
            #pragma unroll
            for (int r = 0; r < 4; r++) {
                int token = tokBase + rt * 16 + quad * 4 + r;
                f32x2 kk; kk[0] = k0[rt][r]; kk[1] = k1[rt][r];
                *(f32x2*)&cand[(size_t)token * (SLICES * 2) + blockIdx.y * 2] = kk;
            }
    }
}

// ---------------------------------------------------------------------------
// K2: 1 token/wave. If the best key beats the 2nd by > MARGIN the winner is
// certain -> gather only. Else exact fp32 re-score of all 8 candidates.
// Loss partial goes to ws (plain store) -- NO contended atomic.
__global__ __launch_bounds__(256) void finalize_kernel(
    const float* __restrict__ x, const float* __restrict__ cb,
    const float* __restrict__ cnorm, const float* __restrict__ cand,
    float* __restrict__ out, float* __restrict__ partials) {

    const int tid = threadIdx.x, w = tid >> 6, lane = tid & 63;
    const int token = blockIdx.x * 4 + w;
    const float* xrow = x + (size_t)token * DDIM;

    // all lanes: load the 8 keys (broadcast), top-2 by max
    f32x4 ka = *(const f32x4*)(cand + (size_t)token * 8);
    f32x4 kb = *(const f32x4*)(cand + (size_t)token * 8 + 4);
    float v[8] = {ka[0], ka[1], ka[2], ka[3], kb[0], kb[1], kb[2], kb[3]};
    float t0 = -INFINITY, t1 = -INFINITY;
    #pragma unroll
    for (int j = 0; j < 8; j++) {
        float m = fminf(t0, v[j]);
        t0 = fmaxf(t0, v[j]);
        t1 = fmaxf(t1, m);
    }
    int bidx = (int)(__float_as_uint(t0) & 0x1FFFu);

    if (!(t0 - t1 > MARGIN)) {
        // exact fp32 re-score of all 8 candidates (8 lanes per candidate)
        const int j = lane >> 3, sub = lane & 7;
        int cj = (int)(__float_as_uint(v[j]) & 0x1FFFu);
        const float* crow = cb + (size_t)cj * DDIM;
        float p = 0.0f;
        #pragma unroll
        for (int c = 0; c < 8; c++) {   // group lanes cover 32 contiguous floats
            f32x4 xa = *(const f32x4*)(xrow + c * 32 + sub * 4);
            f32x4 ca = *(const f32x4*)(crow + c * 32 + sub * 4);
            p += xa[0]*ca[0] + xa[1]*ca[1] + xa[2]*ca[2] + xa[3]*ca[3];
        }
        p += __shfl_xor(p, 1, 64);
        p += __shfl_xor(p, 2, 64);
        p += __shfl_xor(p, 4, 64);
        float bd = cnorm[cj] - 2.0f * p;
        int   bi = cj;
        #pragma unroll
        for (int s = 8; s < 64; s <<= 1) {   // reference tie-break: lower index
            float od = __shfl_xor(bd, s, 64);
            int   oi = __shfl_xor(bi, s, 64);
            if (od < bd || (od == bd && oi < bi)) { bd = od; bi = oi; }
        }
        bidx = bi;
    }

    // common tail: gather winner row, write out, commitment-loss partial
    f32x4 cv = *(const f32x4*)(cb + (size_t)bidx * DDIM + lane * 4);
    f32x4 xv = *(const f32x4*)(xrow + lane * 4);
    *(f32x4*)(out + (size_t)token * DDIM + lane * 4) = cv;
    float d0 = cv[0]-xv[0], d1 = cv[1]-xv[1], d2 = cv[2]-xv[2], d3 = cv[3]-xv[3];
    float lsum = d0*d0 + d1*d1 + d2*d2 + d3*d3;

    __shared__ float red[256];
    red[tid] = lsum;
    __syncthreads();
    #pragma unroll
    for (int s = 128; s > 0; s >>= 1) {
        if (tid < s) red[tid] += red[tid + s];
        __syncthreads();
    }
    if (tid == 0) partials[blockIdx.x] = red[0];
}

// ---------------------------------------------------------------------------
// K3: single-block sum of the 8192 per-block loss partials.
__global__ __launch_bounds__(256) void reduce_loss(const float* __restrict__ partials,
                                                   float* __restrict__ out) {
    const int tid = threadIdx.x;
    float s = 0.0f;
    #pragma unroll
    for (int i = 0; i < 8; i++) {   // 256 threads x 8 x f32x4 = 8192 floats
        f32x4 v = *(const f32x4*)(partials + (size_t)(i * 256 + tid) * 4);
        s += v[0] + v[1] + v[2] + v[3];
    }
    __shared__ float red[256];
    red[tid] = s;
    __syncthreads();
    #pragma unroll
    for (int st = 128; st > 0; st >>= 1) {
        if (tid < st) red[tid] += red[tid + st];
        __syncthreads();
    }
    if (tid == 0)
        out[(size_t)N_TOK * DDIM] = red[0] * (0.25f / (float)((size_t)N_TOK * DDIM));
}

// ---------------------------------------------------------------------------
extern "C" void kernel_launch(void* const* d_in, const int* in_sizes, int n_in,
                              void* d_out, int out_size, void* d_ws, size_t ws_size,
                              hipStream_t stream) {
    const float* x  = (const float*)d_in[0];
    const float* cb = (const float*)d_in[1];
    float* out = (float*)d_out;

    // ws: cb16 (4 MB f16) | cnorm[8192] | cand[32768*8] | partials[8192]
    half_t* cb16     = (half_t*)d_ws;
    float*  cnorm    = (float*)(cb16 + (size_t)KCB * DDIM);
    float*  cand     = cnorm + KCB;
    float*  partials = cand + (size_t)N_TOK * 8;

    prep_cb<<<KCB, 64, 0, stream>>>(cb, cb16, cnorm);
    dim3 gA(N_TOK / 128, SLICES);
    passA<<<gA, 256, 0, stream>>>(x, cb16, cnorm, cand);
    finalize_kernel<<<NFBLK, 256, 0, stream>>>(x, cb, cnorm, cand, out, partials);
    reduce_loss<<<1, 256, 0, stream>>>(partials, out);
}

// Round 8
// 226.647 us; speedup vs baseline: 9.6028x; 1.0741x over previous
//
#include <hip/hip_runtime.h>
#include <math.h>

// x: (64,512,256) f32 -> 32768 tokens x 256 dims. codebook: (8192,256) f32.
#define N_TOK 32768
#define DDIM  256
#define KCB   8192
#define SLICES 4
#define KS     (KCB / SLICES)    // 2048 codes per slice
#define TCODES 64                // codes per LDS tile
#define NSTEP  (KS / TCODES)     // 32 tiles per slice
#define MARGIN 1.0f              // acc-scale gap guaranteeing exact winner
#define NFBLK  (N_TOK / 4)       // finalize blocks (1 token/wave, 4 waves)

typedef _Float16 half_t;
typedef half_t half8 __attribute__((ext_vector_type(8)));
typedef half_t half4 __attribute__((ext_vector_type(4)));
typedef float  f32x4 __attribute__((ext_vector_type(4)));
typedef float  f32x2 __attribute__((ext_vector_type(2)));

#define GLOBAL_AS __attribute__((address_space(1)))
#define LDS_AS    __attribute__((address_space(3)))

// ---------------------------------------------------------------------------
// P0: codebook f32 -> f16 copy + fp32 row norms.
__global__ __launch_bounds__(64) void prep_cb(const float* __restrict__ cb,
                                              half_t* __restrict__ cb16,
                                              float* __restrict__ cnorm) {
    int code = blockIdx.x;
    int lane = threadIdx.x;
    f32x4 v = *(const f32x4*)(cb + (size_t)code * DDIM + lane * 4);
    half4 h; h[0]=(half_t)v[0]; h[1]=(half_t)v[1]; h[2]=(half_t)v[2]; h[3]=(half_t)v[3];
    *(half4*)(cb16 + (size_t)code * DDIM + lane * 4) = h;
    float s = v[0]*v[0] + v[1]*v[1] + v[2]*v[2] + v[3]*v[3];
    #pragma unroll
    for (int off = 32; off > 0; off >>= 1) s += __shfl_down(s, off);
    if (lane == 0) cnorm[code] = s;
}

// load 8 consecutive f32, convert to 8 f16 (prologue only)
__device__ __forceinline__ half8 ldcvt8(const float* __restrict__ p) {
    f32x4 a = *(const f32x4*)p;
    f32x4 b = *(const f32x4*)(p + 4);
    half8 h;
    h[0]=(half_t)a[0]; h[1]=(half_t)a[1]; h[2]=(half_t)a[2]; h[3]=(half_t)a[3];
    h[4]=(half_t)b[0]; h[5]=(half_t)b[1]; h[6]=(half_t)b[2]; h[7]=(half_t)b[3];
    return h;
}

// pack: f32 key with low 13 mantissa bits replaced by code id (sortable)
__device__ __forceinline__ float packkey(float a, unsigned code) {
    return __uint_as_float((__float_as_uint(a) & 0xFFFFE000u) | code);
}

// ---------------------------------------------------------------------------
// Pass A: 256 threads (4 waves), 256 tokens/block (64/wave), one 2048-code
// K-slice. 16x16x32 f16 MFMA; each 16B LDS B-read feeds 4 MFMAs (4 token
// tiles/wave) -> LDS traffic per token halved vs 32-token waves. cnorm
// folded into acc init (acc = dot - cn/2 = -d/2, monotone). 64-code LDS
// tiles (2 x 32 KB double buffer) halve barrier count; tile processed in two
// ct-pair passes to keep acc at 32 regs. Requires 2 waves/EU (256-reg
// budget): afrag 128 + acc 32 + trackers 32 + misc ~30.
__global__ __launch_bounds__(256, 2)
void passA(const float* __restrict__ x, const half_t* __restrict__ cb16,
           const float* __restrict__ cnorm, float* __restrict__ cand) {

    __shared__ __align__(16) half_t buf[2][TCODES * 256];   // 2 x 32 KB

    const int tid  = threadIdx.x;
    const int w    = tid >> 6;
    const int lane = tid & 63;
    const int quad = lane >> 4;
    const int mcol = lane & 15;
    const int tokBase   = blockIdx.x * 256 + w * 64;   // wave's 64 tokens
    const int codeBase0 = blockIdx.y * KS;

    // ---- A fragments: A[m=mcol][k=quad*8+j], full D=256 in regs (128 regs)
    half8 afrag[4][8];
    #pragma unroll
    for (int rt = 0; rt < 4; rt++) {
        const float* xr = x + (size_t)(tokBase + rt * 16 + mcol) * DDIM + quad * 8;
        #pragma unroll
        for (int dk = 0; dk < 8; dk++)
            afrag[rt][dk] = ldcvt8(xr + dk * 32);
    }

    // ---- B-read LDS offsets (halves): row = mcol, chunk = (dk*4+quad)^(mcol&7)
    int boff[8];
    #pragma unroll
    for (int dk = 0; dk < 8; dk++)
        boff[dk] = mcol * 256 + (((dk * 4 + quad) ^ (mcol & 7)) * 8);

    // packed top-2 keys (max semantics) per owned token [rt][r]
    float k0[4][4], k1[4][4];
    #pragma unroll
    for (int rt = 0; rt < 4; rt++)
        #pragma unroll
        for (int r = 0; r < 4; r++) { k0[rt][r] = -INFINITY; k1[rt][r] = -INFINITY; }

    // stage 32 KB tile nt into buffer b (async, swizzled to match read side):
    // 2048 x 16B chunks, 8/thread; dest chunk = o*256 + w*64 + lane.
    const char* cbbase = (const char*)(cb16 + (size_t)codeBase0 * DDIM);
    #define STAGE(nt, b)                                                        \
        {                                                                       \
            const char* srcb = cbbase + (size_t)(nt) * (TCODES * 512);          \
            _Pragma("unroll")                                                   \
            for (int o = 0; o < 8; o++) {                                       \
                int L = o * 256 + tid;                                          \
                int r = L >> 5, c = (L & 31) ^ (r & 7);                         \
                __builtin_amdgcn_global_load_lds(                               \
                    (const GLOBAL_AS void*)(srcb + r * 512 + c * 16),           \
                    (LDS_AS void*)&buf[b][(o * 256 + w * 64) * 8], 16, 0, 0);   \
            }                                                                   \
        }

    STAGE(0, 0)
    __syncthreads();

    for (int nt = 0; nt < NSTEP; nt++) {
        if (nt + 1 < NSTEP) STAGE(nt + 1, (nt + 1) & 1)

        const half_t* cur = buf[nt & 1];
        const int codeBase = codeBase0 + nt * TCODES;

        #pragma unroll
        for (int p = 0; p < 2; p++) {                  // two 32-code passes
            const float mc0 = -0.5f * cnorm[codeBase + p * 32 + mcol];
            const float mc1 = -0.5f * cnorm[codeBase + p * 32 + 16 + mcol];
            f32x4 acc[2][4];
            #pragma unroll
            for (int rt = 0; rt < 4; rt++) {
                acc[0][rt][0]=mc0; acc[0][rt][1]=mc0; acc[0][rt][2]=mc0; acc[0][rt][3]=mc0;
                acc[1][rt][0]=mc1; acc[1][rt][1]=mc1; acc[1][rt][2]=mc1; acc[1][rt][3]=mc1;
            }
            const half_t* crow0 = cur + (p * 32) * 256;
            const half_t* crow1 = cur + (p * 32 + 16) * 256;
            #pragma unroll
            for (int dk = 0; dk < 8; dk++) {
                half8 bf0 = *(const half8*)(crow0 + boff[dk]);
                half8 bf1 = *(const half8*)(crow1 + boff[dk]);
                #pragma unroll
                for (int rt = 0; rt < 4; rt++) {
                    acc[0][rt] = __builtin_amdgcn_mfma_f32_16x16x32_f16(afrag[rt][dk], bf0, acc[0][rt], 0, 0, 0);
                    acc[1][rt] = __builtin_amdgcn_mfma_f32_16x16x32_f16(afrag[rt][dk], bf1, acc[1][rt], 0, 0, 0);
                }
            }
            // C layout: col = lane&15 (code), row = quad*4 + r (token).
            const unsigned code0 = (unsigned)(codeBase + p * 32 + mcol);
            const unsigned code1 = code0 + 16;
            #pragma unroll
            for (int rt = 0; rt < 4; rt++)
                #pragma unroll
                for (int r = 0; r < 4; r++) {
                    float a = packkey(acc[0][rt][r], code0);
                    float b = packkey(acc[1][rt][r], code1);
                    k1[rt][r] = fmaxf(k1[rt][r], __builtin_amdgcn_fmed3f(k0[rt][r], a, b));
                    k0[rt][r] = fmaxf(fmaxf(k0[rt][r], a), b);
                }
        }
        __syncthreads();
    }

    // ---- merge top-2 (max) across the 16 class lanes; lane mcol==0 writes.
    #pragma unroll
    for (int s = 1; s < 16; s <<= 1) {
        #pragma unroll
        for (int rt = 0; rt < 4; rt++)
            #pragma unroll
            for (int r = 0; r < 4; r++) {
                float o0 = __shfl_xor(k0[rt][r], s, 64);
                float o1 = __shfl_xor(k1[rt][r], s, 64);
                float n1 = fmaxf(fminf(k0[rt][r], o0), fmaxf(k1[rt][r], o1));
                k0[rt][r] = fmaxf(k0[rt][r], o0);
                k1[rt][r] = n1;
            }
    }
    if (mcol == 0) {
        #pragma unroll
        for (int rt = 0; rt < 4; rt++)
            #pragma unroll
            for (int r = 0; r < 4; r++) {
                int token = tokBase + rt * 16 + quad * 4 + r;
                f32x2 kk; kk[0] = k0[rt][r]; kk[1] = k1[rt][r];
                *(f32x2*)&cand[(size_t)token * (SLICES * 2) + blockIdx.y * 2] = kk;
            }
    }
}

// ---------------------------------------------------------------------------
// K2: 1 token/wave. If the best key beats the 2nd by > MARGIN the winner is
// certain -> gather only. Else exact fp32 re-score of all 8 candidates.
// Loss partial goes to ws (plain store) -- no contended atomic.
__global__ __launch_bounds__(256) void finalize_kernel(
    const float* __restrict__ x, const float* __restrict__ cb,
    const float* __restrict__ cnorm, const float* __restrict__ cand,
    float* __restrict__ out, float* __restrict__ partials) {

    const int tid = threadIdx.x, w = tid >> 6, lane = tid & 63;
    const int token = blockIdx.x * 4 + w;
    const float* xrow = x + (size_t)token * DDIM;

    // all lanes: load the 8 keys (broadcast), top-2 by max
    f32x4 ka = *(const f32x4*)(cand + (size_t)token * 8);
    f32x4 kb = *(const f32x4*)(cand + (size_t)token * 8 + 4);
    float v[8] = {ka[0], ka[1], ka[2], ka[3], kb[0], kb[1], kb[2], kb[3]};
    float t0 = -INFINITY, t1 = -INFINITY;
    #pragma unroll
    for (int j = 0; j < 8; j++) {
        float m = fminf(t0, v[j]);
        t0 = fmaxf(t0, v[j]);
        t1 = fmaxf(t1, m);
    }
    int bidx = (int)(__float_as_uint(t0) & 0x1FFFu);

    if (!(t0 - t1 > MARGIN)) {
        // exact fp32 re-score of all 8 candidates (8 lanes per candidate)
        const int j = lane >> 3, sub = lane & 7;
        int cj = (int)(__float_as_uint(v[j]) & 0x1FFFu);
        const float* crow = cb + (size_t)cj * DDIM;
        float p = 0.0f;
        #pragma unroll
        for (int c = 0; c < 8; c++) {   // group lanes cover 32 contiguous floats
            f32x4 xa = *(const f32x4*)(xrow + c * 32 + sub * 4);
            f32x4 ca = *(const f32x4*)(crow + c * 32 + sub * 4);
            p += xa[0]*ca[0] + xa[1]*ca[1] + xa[2]*ca[2] + xa[3]*ca[3];
        }
        p += __shfl_xor(p, 1, 64);
        p += __shfl_xor(p, 2, 64);
        p += __shfl_xor(p, 4, 64);
        float bd = cnorm[cj] - 2.0f * p;
        int   bi = cj;
        #pragma unroll
        for (int s = 8; s < 64; s <<= 1) {   // reference tie-break: lower index
            float od = __shfl_xor(bd, s, 64);
            int   oi = __shfl_xor(bi, s, 64);
            if (od < bd || (od == bd && oi < bi)) { bd = od; bi = oi; }
        }
        bidx = bi;
    }

    // common tail: gather winner row, write out, commitment-loss partial
    f32x4 cv = *(const f32x4*)(cb + (size_t)bidx * DDIM + lane * 4);
    f32x4 xv = *(const f32x4*)(xrow + lane * 4);
    *(f32x4*)(out + (size_t)token * DDIM + lane * 4) = cv;
    float d0 = cv[0]-xv[0], d1 = cv[1]-xv[1], d2 = cv[2]-xv[2], d3 = cv[3]-xv[3];
    float lsum = d0*d0 + d1*d1 + d2*d2 + d3*d3;

    __shared__ float red[256];
    red[tid] = lsum;
    __syncthreads();
    #pragma unroll
    for (int s = 128; s > 0; s >>= 1) {
        if (tid < s) red[tid] += red[tid + s];
        __syncthreads();
    }
    if (tid == 0) partials[blockIdx.x] = red[0];
}

// ---------------------------------------------------------------------------
// K3: single-block sum of the 8192 per-block loss partials.
__global__ __launch_bounds__(256) void reduce_loss(const float* __restrict__ partials,
                                                   float* __restrict__ out) {
    const int tid = threadIdx.x;
    float s = 0.0f;
    #pragma unroll
    for (int i = 0; i < 8; i++) {   // 256 threads x 8 x f32x4 = 8192 floats
        f32x4 v = *(const f32x4*)(partials + (size_t)(i * 256 + tid) * 4);
        s += v[0] + v[1] + v[2] + v[3];
    }
    __shared__ float red[256];
    red[tid] = s;
    __syncthreads();
    #pragma unroll
    for (int st = 128; st > 0; st >>= 1) {
        if (tid < st) red[tid] += red[tid + st];
        __syncthreads();
    }
    if (tid == 0)
        out[(size_t)N_TOK * DDIM] = red[0] * (0.25f / (float)((size_t)N_TOK * DDIM));
}

// ---------------------------------------------------------------------------
extern "C" void kernel_launch(void* const* d_in, const int* in_sizes, int n_in,
                              void* d_out, int out_size, void* d_ws, size_t ws_size,
                              hipStream_t stream) {
    const float* x  = (const float*)d_in[0];
    const float* cb = (const float*)d_in[1];
    float* out = (float*)d_out;

    // ws: cb16 (4 MB f16) | cnorm[8192] | cand[32768*8] | partials[8192]
    half_t* cb16     = (half_t*)d_ws;
    float*  cnorm    = (float*)(cb16 + (size_t)KCB * DDIM);
    float*  cand     = cnorm + KCB;
    float*  partials = cand + (size_t)N_TOK * 8;

    prep_cb<<<KCB, 64, 0, stream>>>(cb, cb16, cnorm);
    dim3 gA(N_TOK / 256, SLICES);
    passA<<<gA, 256, 0, stream>>>(x, cb16, cnorm, cand);
    finalize_kernel<<<NFBLK, 256, 0, stream>>>(x, cb, cnorm, cand, out, partials);
    reduce_loss<<<1, 256, 0, stream>>>(partials, out);
}